// Round 13
// baseline (277.690 us; speedup 1.0000x reference)
//
#include <hip/hip_runtime.h>
#include <cmath>

// Problem constants (fixed by the reference)
constexpr int TOT = 131072;   // 32 graphs * 4096 nodes
constexpr int NE  = 1048576;  // edges
constexpr int NMASK = 4095;   // N-1, N=4096

// Bucketed adjacency
constexpr int NB   = 512;     // buckets (dst >> 8)
constexpr int DPB  = 256;     // dsts per bucket
constexpr int BCAP = 4096;    // slots per bucket (mean 2048)
constexpr int EPB  = 2048;    // edges per partition block

typedef __attribute__((ext_vector_type(8))) short bf16x8;
typedef __attribute__((ext_vector_type(4))) float f32x4;

// ---- bf16 helpers (RNE) ----
__device__ inline float bf2f(unsigned int u16) {
    union { unsigned int i; float f; } x; x.i = u16 << 16; return x.f;
}
__device__ inline unsigned short f2bf(float f) {
    union { float f; unsigned int i; } x; x.f = f;
    unsigned int r = (x.i + 0x7fffu + ((x.i >> 16) & 1u)) >> 16;
    return (unsigned short)r;
}
__device__ inline void unpack8(uint4 v, float* f) {
    f[0] = bf2f(v.x & 0xffffu); f[1] = bf2f(v.x >> 16);
    f[2] = bf2f(v.y & 0xffffu); f[3] = bf2f(v.y >> 16);
    f[4] = bf2f(v.z & 0xffffu); f[5] = bf2f(v.z >> 16);
    f[6] = bf2f(v.w & 0xffffu); f[7] = bf2f(v.w >> 16);
}
__device__ inline uint4 pack8(const float* f) {
    uint4 v;
    v.x = (unsigned)f2bf(f[0]) | ((unsigned)f2bf(f[1]) << 16);
    v.y = (unsigned)f2bf(f[2]) | ((unsigned)f2bf(f[3]) << 16);
    v.z = (unsigned)f2bf(f[4]) | ((unsigned)f2bf(f[5]) << 16);
    v.w = (unsigned)f2bf(f[6]) | ((unsigned)f2bf(f[7]) << 16);
    return v;
}

// ---- weight packing into MFMA B-fragment order (device helper) ----
__device__ inline void pack_one(const float* __restrict__ w, unsigned short* __restrict__ wp,
                                int CIN, int COUT, int taps, int idx) {
    int j = idx & 7;
    int L = (idx >> 3) & 63;
    int f = idx >> 9;
    int NT = COUT >> 4;
    int kc = f / NT, nt = f - kc * NT;
    int k = kc * 32 + (L >> 4) * 8 + j;
    int n = nt * 16 + (L & 15);
    float v;
    if (taps == 1) v = w[k * COUT + n];
    else { int t = k / CIN, c = k - t * CIN; v = w[(n * CIN + c) * 3 + t]; }
    wp[idx] = f2bf(v);
}

// ================= edge partition by dst bucket (+ fused weight packing) =================
struct PackArgs {
    const float *W1, *W2, *W3, *tW1, *tW2, *tW3;
    unsigned short *g1, *g2, *g3, *c1, *c2, *c3;
};
__global__ __launch_bounds__(256) void k_part(const int* __restrict__ src,
                                              const int* __restrict__ dst,
                                              int* __restrict__ gcur,
                                              unsigned* __restrict__ buf,
                                              PackArgs pa) {
    __shared__ int hist[NB];
    __shared__ int cbase[NB];
    __shared__ int lcur[NB];
    const int tid = threadIdx.x;
    const int e0 = blockIdx.x * EPB;

    for (int b = tid; b < NB; b += 256) hist[b] = 0;
    __syncthreads();
    for (int i = tid; i < EPB; i += 256)
        atomicAdd(&hist[dst[e0 + i] >> 8], 1);
    __syncthreads();
    for (int b = tid; b < NB; b += 256) {
        int c = hist[b];
        cbase[b] = (c > 0) ? atomicAdd(&gcur[b * 32], c) : 0;
        lcur[b] = 0;
    }
    __syncthreads();
    for (int i = tid; i < EPB; i += 256) {
        int e = e0 + i;
        int d = dst[e];
        int b = d >> 8;
        int p = atomicAdd(&lcur[b], 1);
        buf[b * BCAP + cbase[b] + p] = ((unsigned)src[e] << 8) | (unsigned)(d & 255);
    }
    // fused weight packing
    int gid = blockIdx.x * 256 + tid;
    if      (gid <  8192) pack_one(pa.W1,  pa.g1, 64, 128, 1, gid);
    else if (gid < 12288) pack_one(pa.W2,  pa.g2, 128, 32, 1, gid - 8192);
    else if (gid < 16384) pack_one(pa.W3,  pa.g3, 32, 128, 1, gid - 12288);
    else if (gid < 65536) pack_one(pa.tW1, pa.c1, 128, 128, 3, gid - 16384);
    else if (gid < 77824) pack_one(pa.tW2, pa.c2, 128, 32, 3, gid - 65536);
    else if (gid < 90112) pack_one(pa.tW3, pa.c3, 32, 128, 3, gid - 77824);
}

// ================= per-bucket CSR build + dinv + fused x*dinv scaling =================
__global__ __launch_bounds__(256) void k_bcsr(const unsigned* __restrict__ buf,
                                              const int* __restrict__ gcur,
                                              int* __restrict__ adj,
                                              int2* __restrict__ rse,
                                              float* __restrict__ dinv,
                                              const float4* __restrict__ x,
                                              uint4* __restrict__ xsc) {
    __shared__ int cnt[DPB];
    __shared__ int start[DPB];
    __shared__ int cur[DPB];
    __shared__ int sc[DPB];
    const int b = blockIdx.x;
    const int tid = threadIdx.x;
    cnt[tid] = 0;
    __syncthreads();
    const int n = gcur[b * 32];
    const unsigned* eb = buf + b * BCAP;
    for (int i = tid; i < n; i += 256)
        atomicAdd(&cnt[eb[i] & 255u], 1);
    __syncthreads();
    int v = cnt[tid];
    sc[tid] = v;
    __syncthreads();
    for (int off = 1; off < 256; off <<= 1) {
        int a = sc[tid];
        int p = (tid >= off) ? sc[tid - off] : 0;
        __syncthreads();
        sc[tid] = a + p;
        __syncthreads();
    }
    int st = sc[tid] - v;
    start[tid] = st;
    cur[tid] = 0;
    int d = (b << 8) + tid;
    rse[d] = make_int2(b * BCAP + st, v);
    dinv[d] = rsqrtf((float)v + 1.0f);   // +1 self-loop
    __syncthreads();
    for (int i = tid; i < n; i += 256) {
        unsigned w = eb[i];
        int dl = (int)(w & 255u);
        int p = atomicAdd(&cur[dl], 1);
        adj[b * BCAP + start[dl] + p] = (int)(w >> 8);
    }
    // fused: xs = x * dinv -> bf16 for this bucket's 256 rows
    for (int i = tid; i < DPB * 8; i += 256) {
        int rl = i >> 3;
        int t = (b << 11) + i;                 // global uint4 index (row*8+g)
        float dv = rsqrtf((float)cnt[rl] + 1.0f);
        float4 v0 = x[t * 2], v1 = x[t * 2 + 1];
        float f[8] = { v0.x * dv, v0.y * dv, v0.z * dv, v0.w * dv,
                       v1.x * dv, v1.y * dv, v1.z * dv, v1.w * dv };
        xsc[t] = pack8(f);
    }
}

// ================= standalone CSR gather (layer-2 epilogue) =================
template<int LC>
__global__ __launch_bounds__(256) void k_gcsr(const uint4* __restrict__ xs,
                                              const int* __restrict__ adj,
                                              const int2* __restrict__ rse,
                                              const float* __restrict__ dinv,
                                              const float* __restrict__ bias,
                                              uint4* __restrict__ out) {
    int t = blockIdx.x * 256 + threadIdx.x;   // t < TOT << LC
    int d = t >> LC;
    int g = t & ((1 << LC) - 1);
    float a[8];
    unpack8(xs[t], a);                        // self-loop term
    int2 se = rse[d];
    int e = se.x, end = se.x + se.y;
    for (; e + 4 <= end; e += 4) {
        int s0 = adj[e], s1 = adj[e + 1], s2 = adj[e + 2], s3 = adj[e + 3];
        uint4 v0 = xs[(s0 << LC) + g];
        uint4 v1 = xs[(s1 << LC) + g];
        uint4 v2 = xs[(s2 << LC) + g];
        uint4 v3 = xs[(s3 << LC) + g];
        float f[8];
        unpack8(v0, f);
#pragma unroll
        for (int j = 0; j < 8; ++j) a[j] += f[j];
        unpack8(v1, f);
#pragma unroll
        for (int j = 0; j < 8; ++j) a[j] += f[j];
        unpack8(v2, f);
#pragma unroll
        for (int j = 0; j < 8; ++j) a[j] += f[j];
        unpack8(v3, f);
#pragma unroll
        for (int j = 0; j < 8; ++j) a[j] += f[j];
    }
    for (; e < end; ++e) {
        float f[8];
        unpack8(xs[(adj[e] << LC) + g], f);
#pragma unroll
        for (int j = 0; j < 8; ++j) a[j] += f[j];
    }
    float dv = dinv[d];
#pragma unroll
    for (int j = 0; j < 8; ++j)
        a[j] = fmaxf(fmaf(a[j], dv, bias[g * 8 + j]), 0.0f) * dv;
    out[t] = pack8(a);
}

// ================= fused gather + GEMM1 (64->128) + GEMM2 (128->32) =================
// LDS aliased: tile1 (9.2 KB) and h1t (18.4 KB) share one 18.4 KB array —
// GEMM1 consumes tile1 fully into registers before the barrier, then its
// epilogue overwrites the same LDS as h1t. 27.6 -> 18.4 KB: 8 blocks/CU so
// the MLP-bound gather gets full residency (round-12 counters: fused gather
// ran at 1.7 TB/s vs 3.1 standalone, occupancy-starved).
__global__ __launch_bounds__(256) void k_gmm2(const uint4* __restrict__ xs,
                                              const int* __restrict__ adj,
                                              const int2* __restrict__ rse,
                                              const float* __restrict__ dinv,
                                              const bf16x8* __restrict__ wp1,
                                              const float* __restrict__ b1,
                                              const bf16x8* __restrict__ wp2,
                                              unsigned short* __restrict__ y) {
    constexpr int CIN = 64;
    constexpr int ROWS = 64;
    constexpr int SC  = CIN + 8;          // 72
    constexpr int SCH = 144;
    constexpr int NV = CIN / 8;
    constexpr int VPT = NV / 4;
    __shared__ __attribute__((aligned(16))) unsigned short shl[ROWS * SCH];  // 18.4 KB
    unsigned short* tile1 = shl;          // phase 1 (64x72)
    unsigned short* h1t   = shl;          // phase 2 (64x144), aliased

    const int R0 = blockIdx.x * ROWS;
    const int tid = threadIdx.x;

    // ---- gather/stage phase ----
    {
        int r = R0 + (tid >> 2);
        int g = tid & 3;
        const uint4* base = xs + (long)r * NV + g * VPT;
        float a[VPT * 8];
#pragma unroll
        for (int v = 0; v < VPT; ++v) unpack8(base[v], a + v * 8);   // self-loop
        int2 se = rse[r];
        int e = se.x, end = se.x + se.y;
        for (; e + 4 <= end; e += 4) {
            int s0 = adj[e], s1 = adj[e + 1], s2 = adj[e + 2], s3 = adj[e + 3];
            const uint4* p0 = xs + (long)s0 * NV + g * VPT;
            const uint4* p1 = xs + (long)s1 * NV + g * VPT;
            const uint4* p2 = xs + (long)s2 * NV + g * VPT;
            const uint4* p3 = xs + (long)s3 * NV + g * VPT;
            uint4 v0[VPT], v1[VPT], v2[VPT], v3[VPT];
#pragma unroll
            for (int v = 0; v < VPT; ++v) { v0[v] = p0[v]; v1[v] = p1[v]; v2[v] = p2[v]; v3[v] = p3[v]; }
            float f[VPT * 8];
#pragma unroll
            for (int v = 0; v < VPT; ++v) unpack8(v0[v], f + v * 8);
#pragma unroll
            for (int j = 0; j < VPT * 8; ++j) a[j] += f[j];
#pragma unroll
            for (int v = 0; v < VPT; ++v) unpack8(v1[v], f + v * 8);
#pragma unroll
            for (int j = 0; j < VPT * 8; ++j) a[j] += f[j];
#pragma unroll
            for (int v = 0; v < VPT; ++v) unpack8(v2[v], f + v * 8);
#pragma unroll
            for (int j = 0; j < VPT * 8; ++j) a[j] += f[j];
#pragma unroll
            for (int v = 0; v < VPT; ++v) unpack8(v3[v], f + v * 8);
#pragma unroll
            for (int j = 0; j < VPT * 8; ++j) a[j] += f[j];
        }
        for (; e < end; ++e) {
            const uint4* p0 = xs + (long)adj[e] * NV + g * VPT;
            float f[VPT * 8];
#pragma unroll
            for (int v = 0; v < VPT; ++v) unpack8(p0[v], f + v * 8);
#pragma unroll
            for (int j = 0; j < VPT * 8; ++j) a[j] += f[j];
        }
        float dv = dinv[r];
#pragma unroll
        for (int j = 0; j < VPT * 8; ++j) a[j] *= dv;
        uint4* dst4 = (uint4*)(tile1 + (tid >> 2) * SC + g * VPT * 8);
#pragma unroll
        for (int v = 0; v < VPT; ++v) dst4[v] = pack8(a + v * 8);
    }
    __syncthreads();

    const int lane = tid & 63;
    const int w = tid >> 6;
    const int l16 = lane & 15;
    const int q = lane >> 4;

    // ---- GEMM1: 64 -> 128 (reads tile1 fully into regs, then barrier, then h1t) ----
    {
        f32x4 acc[4][2];
#pragma unroll
        for (int wm = 0; wm < 4; ++wm)
#pragma unroll
            for (int nt = 0; nt < 2; ++nt) acc[wm][nt] = (f32x4){0.f, 0.f, 0.f, 0.f};
        const bf16x8* wpl = wp1 + lane;
        const int nt0 = w * 2;
#pragma unroll
        for (int kc = 0; kc < 2; ++kc) {
            bf16x8 a[4];
#pragma unroll
            for (int wm = 0; wm < 4; ++wm)
                a[wm] = *(const bf16x8*)(tile1 + (wm * 16 + l16) * SC + kc * 32 + q * 8);
            bf16x8 b[2];
#pragma unroll
            for (int nt = 0; nt < 2; ++nt)
                b[nt] = wpl[(kc * 8 + nt0 + nt) * 64];
#pragma unroll
            for (int wm = 0; wm < 4; ++wm)
#pragma unroll
                for (int nt = 0; nt < 2; ++nt)
                    acc[wm][nt] = __builtin_amdgcn_mfma_f32_16x16x32_bf16(a[wm], b[nt], acc[wm][nt], 0, 0, 0);
        }
        __syncthreads();   // all tile1 reads complete before h1t (alias) writes
#pragma unroll
        for (int wm = 0; wm < 4; ++wm) {
#pragma unroll
            for (int nt = 0; nt < 2; ++nt) {
                int col = w * 32 + nt * 16 + l16;
                float bi = b1[col];
#pragma unroll
                for (int r = 0; r < 4; ++r) {
                    int row = wm * 16 + q * 4 + r;
                    h1t[row * SCH + col] = f2bf(fmaxf(acc[wm][nt][r] + bi, 0.0f));
                }
            }
        }
    }
    __syncthreads();

    // ---- GEMM2: 128 -> 32 ----
    {
        const int colbase = (w & 1) * 16;
        const int rowbase = (w >> 1) * 32;
        const int nt0 = colbase >> 4;
        f32x4 acc[2];
#pragma unroll
        for (int wm = 0; wm < 2; ++wm) acc[wm] = (f32x4){0.f, 0.f, 0.f, 0.f};
        const bf16x8* wpl = wp2 + lane;
#pragma unroll
        for (int kc = 0; kc < 4; ++kc) {
            bf16x8 a[2];
#pragma unroll
            for (int wm = 0; wm < 2; ++wm)
                a[wm] = *(const bf16x8*)(h1t + (rowbase + wm * 16 + l16) * SCH + kc * 32 + q * 8);
            bf16x8 b = wpl[(kc * 2 + nt0) * 64];
#pragma unroll
            for (int wm = 0; wm < 2; ++wm)
                acc[wm] = __builtin_amdgcn_mfma_f32_16x16x32_bf16(a[wm], b, acc[wm], 0, 0, 0);
        }
#pragma unroll
        for (int wm = 0; wm < 2; ++wm) {
            int col = colbase + l16;
#pragma unroll
            for (int r = 0; r < 4; ++r) {
                int row = R0 + rowbase + wm * 16 + q * 4 + r;
                float v = acc[wm][r] * dinv[row];
                y[(long)row * 32 + col] = f2bf(v);
            }
        }
    }
}

// ================= fused gather + GEMM3 (32->128) + temporal conv1 =================
// LDS aliased: atile (6.4 KB) and h3t (19 KB) share one 19 KB array.
// 25.6 -> 19 KB: 8 blocks/CU for the MLP-bound gather phase.
__global__ __launch_bounds__(256) void k_gmc1(
    const uint4* __restrict__ xs,        // zs3 [TOT,32] bf16 (4 uint4/row)
    const int* __restrict__ adj,
    const int2* __restrict__ rse,
    const float* __restrict__ dinv,
    const bf16x8* __restrict__ wp3, const float* __restrict__ b3,
    const bf16x8* __restrict__ wpc1, const float* __restrict__ tb1,
    unsigned short* __restrict__ y) {    // conv1 out [TOT,128]
    constexpr int SCA = 40;              // agg tile stride (32+8)
    constexpr int SCH = 144;             // h3 tile stride
    __shared__ __attribute__((aligned(16))) unsigned short shl[66 * SCH];  // 19 KB
    unsigned short* atile = shl;         // phase 1 (80x40 = 6.4 KB)
    unsigned short* h3t   = shl;         // phase 2 (66x144), aliased

    const int R0 = blockIdx.x * 64;
    const int n0 = R0 & NMASK;
    const int tid = threadIdx.x;

    // zero atile pad rows 66..79 (read by the 5th masked row-tile)
    for (int i = tid; i < 14 * 5; i += 256) {
        int r = 66 + i / 5, c = i % 5;
        *(uint4*)(atile + r * SCA + c * 8) = make_uint4(0, 0, 0, 0);
    }

    // ---- gather phase: agg3 = (self + sum) * dinv for rows [R0-1, R0+65) ----
    for (int it = tid; it < 66 * 4; it += 256) {
        int rr = it >> 2, g = it & 3;
        int n = n0 - 1 + rr;
        float a[8] = {0.f, 0.f, 0.f, 0.f, 0.f, 0.f, 0.f, 0.f};
        if (n >= 0 && n < 4096) {
            int gr = R0 - 1 + rr;
            unpack8(xs[gr * 4 + g], a);                  // self-loop
            int2 se = rse[gr];
            int e = se.x, end = se.x + se.y;
            for (; e + 4 <= end; e += 4) {
                int s0 = adj[e], s1 = adj[e + 1], s2 = adj[e + 2], s3 = adj[e + 3];
                uint4 v0 = xs[(s0 << 2) + g];
                uint4 v1 = xs[(s1 << 2) + g];
                uint4 v2 = xs[(s2 << 2) + g];
                uint4 v3 = xs[(s3 << 2) + g];
                float f[8];
                unpack8(v0, f);
#pragma unroll
                for (int j = 0; j < 8; ++j) a[j] += f[j];
                unpack8(v1, f);
#pragma unroll
                for (int j = 0; j < 8; ++j) a[j] += f[j];
                unpack8(v2, f);
#pragma unroll
                for (int j = 0; j < 8; ++j) a[j] += f[j];
                unpack8(v3, f);
#pragma unroll
                for (int j = 0; j < 8; ++j) a[j] += f[j];
            }
            for (; e < end; ++e) {
                float f[8];
                unpack8(xs[(adj[e] << 2) + g], f);
#pragma unroll
                for (int j = 0; j < 8; ++j) a[j] += f[j];
            }
            float dv = dinv[gr];
#pragma unroll
            for (int j = 0; j < 8; ++j) a[j] *= dv;
        }
        *(uint4*)(atile + rr * SCA + g * 8) = pack8(a);
    }
    __syncthreads();

    const int lane = tid & 63;
    const int w = tid >> 6;
    const int l16 = lane & 15;
    const int q = lane >> 4;

    // ---- GEMM3: 32 -> 128 on 66 rows (reads atile into regs, barrier, h3t) ----
    {
        f32x4 acc[5][2];
#pragma unroll
        for (int rt = 0; rt < 5; ++rt)
#pragma unroll
            for (int nt = 0; nt < 2; ++nt) acc[rt][nt] = (f32x4){0.f, 0.f, 0.f, 0.f};
        const bf16x8* wpl = wp3 + lane;
        bf16x8 b[2];
        b[0] = wpl[(w * 2 + 0) * 64];
        b[1] = wpl[(w * 2 + 1) * 64];
#pragma unroll
        for (int rt = 0; rt < 5; ++rt) {
            bf16x8 a = *(const bf16x8*)(atile + (16 * rt + l16) * SCA + q * 8);
            acc[rt][0] = __builtin_amdgcn_mfma_f32_16x16x32_bf16(a, b[0], acc[rt][0], 0, 0, 0);
            acc[rt][1] = __builtin_amdgcn_mfma_f32_16x16x32_bf16(a, b[1], acc[rt][1], 0, 0, 0);
        }
        __syncthreads();   // all atile reads complete before h3t (alias) writes
#pragma unroll
        for (int rt = 0; rt < 5; ++rt) {
#pragma unroll
            for (int nt = 0; nt < 2; ++nt) {
                int col = w * 32 + nt * 16 + l16;
                float bi = b3[col];
#pragma unroll
                for (int r = 0; r < 4; ++r) {
                    int rr = 16 * rt + q * 4 + r;
                    if (rr < 66) {
                        int n = n0 - 1 + rr;
                        unsigned short v = 0;
                        if (n >= 0 && n < 4096)
                            v = f2bf(fmaxf(acc[rt][nt][r] + bi, 0.0f));
                        h3t[rr * SCH + col] = v;
                    }
                }
            }
        }
    }
    __syncthreads();

    // ---- conv1: 128->128 k=3; out row R0+j reads h3t rows j..j+2 ----
    {
        f32x4 acc[4][2];
#pragma unroll
        for (int rt = 0; rt < 4; ++rt)
#pragma unroll
            for (int nt = 0; nt < 2; ++nt) acc[rt][nt] = (f32x4){0.f, 0.f, 0.f, 0.f};
        const bf16x8* wpl = wpc1 + lane;
#pragma unroll
        for (int kc = 0; kc < 12; ++kc) {
            int tap = kc >> 2, ch = kc & 3;
            bf16x8 a[4];
#pragma unroll
            for (int rt = 0; rt < 4; ++rt)
                a[rt] = *(const bf16x8*)(h3t + (16 * rt + l16 + tap) * SCH + ch * 32 + q * 8);
            bf16x8 b0 = wpl[(kc * 8 + 2 * w + 0) * 64];
            bf16x8 b1 = wpl[(kc * 8 + 2 * w + 1) * 64];
#pragma unroll
            for (int rt = 0; rt < 4; ++rt) {
                acc[rt][0] = __builtin_amdgcn_mfma_f32_16x16x32_bf16(a[rt], b0, acc[rt][0], 0, 0, 0);
                acc[rt][1] = __builtin_amdgcn_mfma_f32_16x16x32_bf16(a[rt], b1, acc[rt][1], 0, 0, 0);
            }
        }
#pragma unroll
        for (int rt = 0; rt < 4; ++rt) {
#pragma unroll
            for (int nt = 0; nt < 2; ++nt) {
                int col = w * 32 + nt * 16 + l16;
                float bi = tb1[col];
#pragma unroll
                for (int r = 0; r < 4; ++r) {
                    int row = R0 + 16 * rt + q * 4 + r;
                    y[(long)row * 128 + col] = f2bf(fmaxf(acc[rt][nt][r] + bi, 0.0f));
                }
            }
        }
    }
}

// ================= fused conv2 (128->32) + conv3 (32->128) + heads =================
__global__ __launch_bounds__(256) void k_c23_heads(
    const unsigned short* __restrict__ x,      // conv1 output [TOT,128] bf16
    const bf16x8* __restrict__ wp2, const float* __restrict__ tb2,
    const bf16x8* __restrict__ wp3, const float* __restrict__ tb3,
    const float* __restrict__ Wpi, const float* __restrict__ bpi,
    const float* __restrict__ Wn,  const float* __restrict__ bn,
    const float* __restrict__ Wp,  const float* __restrict__ bp,
    float* __restrict__ out) {
    constexpr int SC1 = 136;
    constexpr int SC2 = 40;
    __shared__ __attribute__((aligned(16))) unsigned short shl[82 * 136 + 66 * 40];
    unsigned short* c1  = shl;                // 82 rows: global [R0-2, R0+80)
    unsigned short* c2  = shl + 82 * 136;     // 66 rows: global [R0-1, R0+65)
    unsigned short* xts = shl;                // alias (c1 dead after conv2)

    const int R0 = blockIdx.x * 64;
    const int n0 = R0 & NMASK;
    const int tid = threadIdx.x;

    for (int i = tid; i < 82 * 16; i += 256) {
        int r = i >> 4;
        int c8 = i & 15;
        int n = n0 - 2 + r;
        uint4 v = make_uint4(0, 0, 0, 0);
        if (n >= 0 && n < 4096)
            v = *(const uint4*)(x + (long)(R0 - 2 + r) * 128 + c8 * 8);
        *(uint4*)(c1 + r * SC1 + c8 * 8) = v;
    }
    __syncthreads();

    const int lane = tid & 63;
    const int w = tid >> 6;
    const int l16 = lane & 15;
    const int q = lane >> 4;

    // ---- conv2: 128->32, 5 row-tiles, wave rts {w, w+4} ----
    for (int rt = w; rt < 5; rt += 4) {
        f32x4 acc[2];
#pragma unroll
        for (int nt = 0; nt < 2; ++nt) acc[nt] = (f32x4){0.f, 0.f, 0.f, 0.f};
        const bf16x8* wpl = wp2 + lane;
#pragma unroll
        for (int kc = 0; kc < 12; ++kc) {
            int tap = kc >> 2, ch = kc & 3;
            bf16x8 a = *(const bf16x8*)(c1 + (16 * rt + l16 + tap) * SC1 + ch * 32 + q * 8);
            bf16x8 b0 = wpl[(kc * 2 + 0) * 64];
            bf16x8 b1 = wpl[(kc * 2 + 1) * 64];
            acc[0] = __builtin_amdgcn_mfma_f32_16x16x32_bf16(a, b0, acc[0], 0, 0, 0);
            acc[1] = __builtin_amdgcn_mfma_f32_16x16x32_bf16(a, b1, acc[1], 0, 0, 0);
        }
#pragma unroll
        for (int nt = 0; nt < 2; ++nt) {
            int col = nt * 16 + l16;
            float bi = tb2[col];
#pragma unroll
            for (int r = 0; r < 4; ++r) {
                int idx = 16 * rt + q * 4 + r;
                if (idx < 66) {
                    int n = n0 - 1 + idx;
                    unsigned short v = 0;
                    if (n >= 0 && n < 4096)
                        v = f2bf(fmaxf(acc[nt][r] + bi, 0.0f));
                    c2[idx * SC2 + col] = v;
                }
            }
        }
    }
    __syncthreads();

    // ---- conv3: 32->128, 4 row-tiles at R0; write xts ----
    {
        f32x4 acc[4][2];
#pragma unroll
        for (int rt = 0; rt < 4; ++rt)
#pragma unroll
            for (int nt = 0; nt < 2; ++nt) acc[rt][nt] = (f32x4){0.f, 0.f, 0.f, 0.f};
        const bf16x8* wpl = wp3 + lane;
#pragma unroll
        for (int kc = 0; kc < 3; ++kc) {
            bf16x8 a[4];
#pragma unroll
            for (int rt = 0; rt < 4; ++rt)
                a[rt] = *(const bf16x8*)(c2 + (16 * rt + l16 + kc) * SC2 + q * 8);
            bf16x8 b[2];
#pragma unroll
            for (int nt = 0; nt < 2; ++nt)
                b[nt] = wpl[(kc * 8 + 2 * w + nt) * 64];
#pragma unroll
            for (int rt = 0; rt < 4; ++rt)
#pragma unroll
                for (int nt = 0; nt < 2; ++nt)
                    acc[rt][nt] = __builtin_amdgcn_mfma_f32_16x16x32_bf16(a[rt], b[nt], acc[rt][nt], 0, 0, 0);
        }
#pragma unroll
        for (int rt = 0; rt < 4; ++rt) {
#pragma unroll
            for (int nt = 0; nt < 2; ++nt) {
                int col = w * 32 + nt * 16 + l16;
                float bi = tb3[col];
#pragma unroll
                for (int r = 0; r < 4; ++r) {
                    int row = 16 * rt + q * 4 + r;
                    xts[row * 130 + col] = f2bf(fmaxf(acc[rt][nt][r] + bi, 0.0f));
                }
            }
        }
    }
    __syncthreads();

    // ---- heads ----
    if (tid < 192) {
        int h = tid >> 6;
        int row = tid & 63;
        const float* Wh = (h == 0) ? Wpi : (h == 1) ? Wn : Wp;
        float s = 0.0f;
        const unsigned short* xr = xts + row * 130;
#pragma unroll
        for (int c2i = 0; c2i < 64; ++c2i) {
            unsigned u = *(const unsigned*)(xr + c2i * 2);
            s = fmaf(bf2f(u & 0xffffu), Wh[c2i * 2], s);
            s = fmaf(bf2f(u >> 16), Wh[c2i * 2 + 1], s);
        }
        float bb = (h == 0) ? bpi[0] : (h == 1) ? bn[0] : bp[0];
        float z = s + bb;
        float o;
        if (h == 1) o = (z > 20.0f) ? z : log1pf(expf(z));
        else        o = 1.0f / (1.0f + expf(-z));
        out[h * TOT + R0 + row] = o;
    }
}

extern "C" void kernel_launch(void* const* d_in, const int* in_sizes, int n_in,
                              void* d_out, int out_size, void* d_ws, size_t ws_size,
                              hipStream_t stream) {
    const float* x   = (const float*)d_in[0];
    const int*   ei  = (const int*)d_in[1];
    const int*   src = ei;
    const int*   dst = ei + NE;
    const float* W1 = (const float*)d_in[3];
    const float* b1 = (const float*)d_in[4];
    const float* W2 = (const float*)d_in[5];
    const float* b2 = (const float*)d_in[6];
    const float* W3 = (const float*)d_in[7];
    const float* b3 = (const float*)d_in[8];
    const float* tW1 = (const float*)d_in[9];
    const float* tb1 = (const float*)d_in[10];
    const float* tW2 = (const float*)d_in[11];
    const float* tb2 = (const float*)d_in[12];
    const float* tW3 = (const float*)d_in[13];
    const float* tb3 = (const float*)d_in[14];
    const float* Wpi = (const float*)d_in[15];
    const float* bpi = (const float*)d_in[16];
    const float* Wn  = (const float*)d_in[17];
    const float* bn  = (const float*)d_in[18];
    const float* Wp  = (const float*)d_in[19];
    const float* bp  = (const float*)d_in[20];

    // ---- workspace layout ----
    char* ws = (char*)d_ws;
    float* dinv = (float*)(ws + (0ull << 20));            // 512 KB
    int*   gcur = (int*)  (ws + (1ull << 20));            // 64 KB (line-padded)
    int2*  rse  = (int2*) (ws + (1ull << 20) + (256 << 10)); // 1 MB
    unsigned short* wpG1 = (unsigned short*)(ws + (3ull << 20));
    unsigned short* wpG2 = (unsigned short*)(ws + (3ull << 20) + (128 << 10));
    unsigned short* wpG3 = (unsigned short*)(ws + (3ull << 20) + (256 << 10));
    unsigned short* wpC1 = (unsigned short*)(ws + (3ull << 20) + (384 << 10));
    unsigned short* wpC2 = (unsigned short*)(ws + (3ull << 20) + (512 << 10));
    unsigned short* wpC3 = (unsigned short*)(ws + (3ull << 20) + (640 << 10));
    unsigned* buf = (unsigned*)(ws + (4ull << 20));       // 8 MB
    int* adj = (int*)(ws + (12ull << 20));                // 8 MB
    unsigned short* Xa = (unsigned short*)(ws + (24ull  << 20));  // 64ch  16.8 MB
    unsigned short* Xc = (unsigned short*)(ws + (80ull  << 20));  // 128ch 33.6 MB
    unsigned short* Xd = (unsigned short*)(ws + (116ull << 20));  // 32ch   8.4 MB
    unsigned short* Xe = (unsigned short*)(ws + (128ull << 20));  // 32ch   8.4 MB

    // ---- prep ----
    hipMemsetAsync(gcur, 0, NB * 32 * sizeof(int), stream);

    // ---- adjacency: bucket partition (+ fused weight packing) + per-bucket CSR ----
    PackArgs pa = { W1, W2, W3, tW1, tW2, tW3, wpG1, wpG2, wpG3, wpC1, wpC2, wpC3 };
    k_part<<<NE / EPB, 256, 0, stream>>>(src, dst, gcur, buf, pa);
    k_bcsr<<<NB, 256, 0, stream>>>(buf, gcur, adj, rse, dinv, (const float4*)x, (uint4*)Xa);

    // ---- GCN layers 1+2a fused: gather + GEMM1 + GEMM2 -> zs2 ----
    k_gmm2<<<TOT / 64, 256, 0, stream>>>((const uint4*)Xa, adj, rse, dinv,
                                         (const bf16x8*)wpG1, b1, (const bf16x8*)wpG2, Xd);

    // ---- GCN layer 2b: zs3 = relu(agg(zs2)*dinv + b2)*dinv ----
    k_gcsr<2><<<TOT * 4 / 256, 256, 0, stream>>>((const uint4*)Xd, adj, rse, dinv,
                                                 b2, (uint4*)Xe);

    // ---- GCN layer 3 + temporal conv1 fused: gather + GEMM3 + conv1 -> Xc ----
    k_gmc1<<<TOT / 64, 256, 0, stream>>>((const uint4*)Xe, adj, rse, dinv,
                                         (const bf16x8*)wpG3, b3,
                                         (const bf16x8*)wpC1, tb1, Xc);

    // ---- conv2 + conv3 + heads fused ----
    k_c23_heads<<<TOT / 64, 256, 0, stream>>>(Xc,
                                              (const bf16x8*)wpC2, tb2,
                                              (const bf16x8*)wpC3, tb3,
                                              Wpi, bpi, Wn, bn, Wp, bp, (float*)d_out);
}

// Round 14
// 269.328 us; speedup vs baseline: 1.0310x; 1.0310x over previous
//
#include <hip/hip_runtime.h>
#include <cmath>

// Problem constants (fixed by the reference)
constexpr int TOT = 131072;   // 32 graphs * 4096 nodes
constexpr int NE  = 1048576;  // edges
constexpr int NMASK = 4095;   // N-1, N=4096

// Bucketed adjacency
constexpr int NB   = 512;     // buckets (dst >> 8)
constexpr int DPB  = 256;     // dsts per bucket
constexpr int BCAP = 4096;    // slots per bucket (mean 2048)
constexpr int EPB  = 2048;    // edges per partition block

typedef __attribute__((ext_vector_type(8))) short bf16x8;
typedef __attribute__((ext_vector_type(4))) float f32x4;

// ---- bf16 helpers (RNE) ----
__device__ inline float bf2f(unsigned int u16) {
    union { unsigned int i; float f; } x; x.i = u16 << 16; return x.f;
}
__device__ inline unsigned short f2bf(float f) {
    union { float f; unsigned int i; } x; x.f = f;
    unsigned int r = (x.i + 0x7fffu + ((x.i >> 16) & 1u)) >> 16;
    return (unsigned short)r;
}
__device__ inline void unpack8(uint4 v, float* f) {
    f[0] = bf2f(v.x & 0xffffu); f[1] = bf2f(v.x >> 16);
    f[2] = bf2f(v.y & 0xffffu); f[3] = bf2f(v.y >> 16);
    f[4] = bf2f(v.z & 0xffffu); f[5] = bf2f(v.z >> 16);
    f[6] = bf2f(v.w & 0xffffu); f[7] = bf2f(v.w >> 16);
}
__device__ inline uint4 pack8(const float* f) {
    uint4 v;
    v.x = (unsigned)f2bf(f[0]) | ((unsigned)f2bf(f[1]) << 16);
    v.y = (unsigned)f2bf(f[2]) | ((unsigned)f2bf(f[3]) << 16);
    v.z = (unsigned)f2bf(f[4]) | ((unsigned)f2bf(f[5]) << 16);
    v.w = (unsigned)f2bf(f[6]) | ((unsigned)f2bf(f[7]) << 16);
    return v;
}

// ---- weight packing into MFMA B-fragment order (device helper) ----
__device__ inline void pack_one(const float* __restrict__ w, unsigned short* __restrict__ wp,
                                int CIN, int COUT, int taps, int idx) {
    int j = idx & 7;
    int L = (idx >> 3) & 63;
    int f = idx >> 9;
    int NT = COUT >> 4;
    int kc = f / NT, nt = f - kc * NT;
    int k = kc * 32 + (L >> 4) * 8 + j;
    int n = nt * 16 + (L & 15);
    float v;
    if (taps == 1) v = w[k * COUT + n];
    else { int t = k / CIN, c = k - t * CIN; v = w[(n * CIN + c) * 3 + t]; }
    wp[idx] = f2bf(v);
}

// ================= edge partition by dst bucket (+ fused weight packing) =================
struct PackArgs {
    const float *W1, *W2, *W3, *tW1, *tW2, *tW3;
    unsigned short *g1, *g2, *g3, *c1, *c2, *c3;
};
__global__ __launch_bounds__(256) void k_part(const int* __restrict__ src,
                                              const int* __restrict__ dst,
                                              int* __restrict__ gcur,
                                              unsigned* __restrict__ buf,
                                              PackArgs pa) {
    __shared__ int hist[NB];
    __shared__ int cbase[NB];
    __shared__ int lcur[NB];
    const int tid = threadIdx.x;
    const int e0 = blockIdx.x * EPB;

    for (int b = tid; b < NB; b += 256) hist[b] = 0;
    __syncthreads();
    for (int i = tid; i < EPB; i += 256)
        atomicAdd(&hist[dst[e0 + i] >> 8], 1);
    __syncthreads();
    for (int b = tid; b < NB; b += 256) {
        int c = hist[b];
        cbase[b] = (c > 0) ? atomicAdd(&gcur[b * 32], c) : 0;
        lcur[b] = 0;
    }
    __syncthreads();
    for (int i = tid; i < EPB; i += 256) {
        int e = e0 + i;
        int d = dst[e];
        int b = d >> 8;
        int p = atomicAdd(&lcur[b], 1);
        buf[b * BCAP + cbase[b] + p] = ((unsigned)src[e] << 8) | (unsigned)(d & 255);
    }
    // fused weight packing
    int gid = blockIdx.x * 256 + tid;
    if      (gid <  8192) pack_one(pa.W1,  pa.g1, 64, 128, 1, gid);
    else if (gid < 12288) pack_one(pa.W2,  pa.g2, 128, 32, 1, gid - 8192);
    else if (gid < 16384) pack_one(pa.W3,  pa.g3, 32, 128, 1, gid - 12288);
    else if (gid < 65536) pack_one(pa.tW1, pa.c1, 128, 128, 3, gid - 16384);
    else if (gid < 77824) pack_one(pa.tW2, pa.c2, 128, 32, 3, gid - 65536);
    else if (gid < 90112) pack_one(pa.tW3, pa.c3, 32, 128, 3, gid - 77824);
}

// ================= per-bucket CSR build + dinv + fused x*dinv scaling =================
__global__ __launch_bounds__(256) void k_bcsr(const unsigned* __restrict__ buf,
                                              const int* __restrict__ gcur,
                                              int* __restrict__ adj,
                                              int2* __restrict__ rse,
                                              float* __restrict__ dinv,
                                              const float4* __restrict__ x,
                                              uint4* __restrict__ xsc) {
    __shared__ int cnt[DPB];
    __shared__ int start[DPB];
    __shared__ int cur[DPB];
    __shared__ int sc[DPB];
    const int b = blockIdx.x;
    const int tid = threadIdx.x;
    cnt[tid] = 0;
    __syncthreads();
    const int n = gcur[b * 32];
    const unsigned* eb = buf + b * BCAP;
    for (int i = tid; i < n; i += 256)
        atomicAdd(&cnt[eb[i] & 255u], 1);
    __syncthreads();
    int v = cnt[tid];
    sc[tid] = v;
    __syncthreads();
    for (int off = 1; off < 256; off <<= 1) {
        int a = sc[tid];
        int p = (tid >= off) ? sc[tid - off] : 0;
        __syncthreads();
        sc[tid] = a + p;
        __syncthreads();
    }
    int st = sc[tid] - v;
    start[tid] = st;
    cur[tid] = 0;
    int d = (b << 8) + tid;
    rse[d] = make_int2(b * BCAP + st, v);
    dinv[d] = rsqrtf((float)v + 1.0f);   // +1 self-loop
    __syncthreads();
    for (int i = tid; i < n; i += 256) {
        unsigned w = eb[i];
        int dl = (int)(w & 255u);
        int p = atomicAdd(&cur[dl], 1);
        adj[b * BCAP + start[dl] + p] = (int)(w >> 8);
    }
    // fused: xs = x * dinv -> bf16 for this bucket's 256 rows
    for (int i = tid; i < DPB * 8; i += 256) {
        int rl = i >> 3;
        int t = (b << 11) + i;                 // global uint4 index (row*8+g)
        float dv = rsqrtf((float)cnt[rl] + 1.0f);
        float4 v0 = x[t * 2], v1 = x[t * 2 + 1];
        float f[8] = { v0.x * dv, v0.y * dv, v0.z * dv, v0.w * dv,
                       v1.x * dv, v1.y * dv, v1.z * dv, v1.w * dv };
        xsc[t] = pack8(f);
    }
}

// ================= standalone CSR gather (layer-2 epilogue) =================
template<int LC>
__global__ __launch_bounds__(256, 8) void k_gcsr(const uint4* __restrict__ xs,
                                                 const int* __restrict__ adj,
                                                 const int2* __restrict__ rse,
                                                 const float* __restrict__ dinv,
                                                 const float* __restrict__ bias,
                                                 uint4* __restrict__ out) {
    int t = blockIdx.x * 256 + threadIdx.x;   // t < TOT << LC
    int d = t >> LC;
    int g = t & ((1 << LC) - 1);
    float a[8];
    unpack8(xs[t], a);                        // self-loop term
    int2 se = rse[d];
    int e = se.x, end = se.x + se.y;
    for (; e + 4 <= end; e += 4) {
        int s0 = adj[e], s1 = adj[e + 1], s2 = adj[e + 2], s3 = adj[e + 3];
        uint4 v0 = xs[(s0 << LC) + g];
        uint4 v1 = xs[(s1 << LC) + g];
        uint4 v2 = xs[(s2 << LC) + g];
        uint4 v3 = xs[(s3 << LC) + g];
        float f[8];
        unpack8(v0, f);
#pragma unroll
        for (int j = 0; j < 8; ++j) a[j] += f[j];
        unpack8(v1, f);
#pragma unroll
        for (int j = 0; j < 8; ++j) a[j] += f[j];
        unpack8(v2, f);
#pragma unroll
        for (int j = 0; j < 8; ++j) a[j] += f[j];
        unpack8(v3, f);
#pragma unroll
        for (int j = 0; j < 8; ++j) a[j] += f[j];
    }
    for (; e < end; ++e) {
        float f[8];
        unpack8(xs[(adj[e] << LC) + g], f);
#pragma unroll
        for (int j = 0; j < 8; ++j) a[j] += f[j];
    }
    float dv = dinv[d];
#pragma unroll
    for (int j = 0; j < 8; ++j)
        a[j] = fmaxf(fmaf(a[j], dv, bias[g * 8 + j]), 0.0f) * dv;
    out[t] = pack8(a);
}

// ================= fused gather + GEMM1 (64->128) + GEMM2 (128->32) =================
// __launch_bounds__(256, 8): force VGPR <= 64. Round-13 counters: 68 VGPR sat
// just over the 64 cliff (m69: waves/CU halve at vgpr=64) -> gather phase ran
// at half concurrency (occupancy 25%, 1.7 TB/s vs 3.1 standalone).
__global__ __launch_bounds__(256, 8) void k_gmm2(const uint4* __restrict__ xs,
                                                 const int* __restrict__ adj,
                                                 const int2* __restrict__ rse,
                                                 const float* __restrict__ dinv,
                                                 const bf16x8* __restrict__ wp1,
                                                 const float* __restrict__ b1,
                                                 const bf16x8* __restrict__ wp2,
                                                 unsigned short* __restrict__ y) {
    constexpr int CIN = 64;
    constexpr int ROWS = 64;
    constexpr int SC  = CIN + 8;          // 72
    constexpr int SCH = 144;
    constexpr int NV = CIN / 8;
    constexpr int VPT = NV / 4;
    __shared__ __attribute__((aligned(16))) unsigned short shl[ROWS * SCH];  // 18.4 KB
    unsigned short* tile1 = shl;          // phase 1 (64x72)
    unsigned short* h1t   = shl;          // phase 2 (64x144), aliased

    const int R0 = blockIdx.x * ROWS;
    const int tid = threadIdx.x;

    // ---- gather/stage phase ----
    {
        int r = R0 + (tid >> 2);
        int g = tid & 3;
        const uint4* base = xs + (long)r * NV + g * VPT;
        float a[VPT * 8];
#pragma unroll
        for (int v = 0; v < VPT; ++v) unpack8(base[v], a + v * 8);   // self-loop
        int2 se = rse[r];
        int e = se.x, end = se.x + se.y;
        for (; e + 4 <= end; e += 4) {
            int s0 = adj[e], s1 = adj[e + 1], s2 = adj[e + 2], s3 = adj[e + 3];
            const uint4* p0 = xs + (long)s0 * NV + g * VPT;
            const uint4* p1 = xs + (long)s1 * NV + g * VPT;
            const uint4* p2 = xs + (long)s2 * NV + g * VPT;
            const uint4* p3 = xs + (long)s3 * NV + g * VPT;
            uint4 v0[VPT], v1[VPT], v2[VPT], v3[VPT];
#pragma unroll
            for (int v = 0; v < VPT; ++v) { v0[v] = p0[v]; v1[v] = p1[v]; v2[v] = p2[v]; v3[v] = p3[v]; }
            float f[VPT * 8];
#pragma unroll
            for (int v = 0; v < VPT; ++v) unpack8(v0[v], f + v * 8);
#pragma unroll
            for (int j = 0; j < VPT * 8; ++j) a[j] += f[j];
#pragma unroll
            for (int v = 0; v < VPT; ++v) unpack8(v1[v], f + v * 8);
#pragma unroll
            for (int j = 0; j < VPT * 8; ++j) a[j] += f[j];
#pragma unroll
            for (int v = 0; v < VPT; ++v) unpack8(v2[v], f + v * 8);
#pragma unroll
            for (int j = 0; j < VPT * 8; ++j) a[j] += f[j];
#pragma unroll
            for (int v = 0; v < VPT; ++v) unpack8(v3[v], f + v * 8);
#pragma unroll
            for (int j = 0; j < VPT * 8; ++j) a[j] += f[j];
        }
        for (; e < end; ++e) {
            const uint4* p0 = xs + (long)adj[e] * NV + g * VPT;
            float f[VPT * 8];
#pragma unroll
            for (int v = 0; v < VPT; ++v) unpack8(p0[v], f + v * 8);
#pragma unroll
            for (int j = 0; j < VPT * 8; ++j) a[j] += f[j];
        }
        float dv = dinv[r];
#pragma unroll
        for (int j = 0; j < VPT * 8; ++j) a[j] *= dv;
        uint4* dst4 = (uint4*)(tile1 + (tid >> 2) * SC + g * VPT * 8);
#pragma unroll
        for (int v = 0; v < VPT; ++v) dst4[v] = pack8(a + v * 8);
    }
    __syncthreads();

    const int lane = tid & 63;
    const int w = tid >> 6;
    const int l16 = lane & 15;
    const int q = lane >> 4;

    // ---- GEMM1: 64 -> 128 (reads tile1 fully into regs, then barrier, then h1t) ----
    {
        f32x4 acc[4][2];
#pragma unroll
        for (int wm = 0; wm < 4; ++wm)
#pragma unroll
            for (int nt = 0; nt < 2; ++nt) acc[wm][nt] = (f32x4){0.f, 0.f, 0.f, 0.f};
        const bf16x8* wpl = wp1 + lane;
        const int nt0 = w * 2;
#pragma unroll
        for (int kc = 0; kc < 2; ++kc) {
            bf16x8 a[4];
#pragma unroll
            for (int wm = 0; wm < 4; ++wm)
                a[wm] = *(const bf16x8*)(tile1 + (wm * 16 + l16) * SC + kc * 32 + q * 8);
            bf16x8 b[2];
#pragma unroll
            for (int nt = 0; nt < 2; ++nt)
                b[nt] = wpl[(kc * 8 + nt0 + nt) * 64];
#pragma unroll
            for (int wm = 0; wm < 4; ++wm)
#pragma unroll
                for (int nt = 0; nt < 2; ++nt)
                    acc[wm][nt] = __builtin_amdgcn_mfma_f32_16x16x32_bf16(a[wm], b[nt], acc[wm][nt], 0, 0, 0);
        }
        __syncthreads();   // all tile1 reads complete before h1t (alias) writes
#pragma unroll
        for (int wm = 0; wm < 4; ++wm) {
#pragma unroll
            for (int nt = 0; nt < 2; ++nt) {
                int col = w * 32 + nt * 16 + l16;
                float bi = b1[col];
#pragma unroll
                for (int r = 0; r < 4; ++r) {
                    int row = wm * 16 + q * 4 + r;
                    h1t[row * SCH + col] = f2bf(fmaxf(acc[wm][nt][r] + bi, 0.0f));
                }
            }
        }
    }
    __syncthreads();

    // ---- GEMM2: 128 -> 32 ----
    {
        const int colbase = (w & 1) * 16;
        const int rowbase = (w >> 1) * 32;
        const int nt0 = colbase >> 4;
        f32x4 acc[2];
#pragma unroll
        for (int wm = 0; wm < 2; ++wm) acc[wm] = (f32x4){0.f, 0.f, 0.f, 0.f};
        const bf16x8* wpl = wp2 + lane;
#pragma unroll
        for (int kc = 0; kc < 4; ++kc) {
            bf16x8 a[2];
#pragma unroll
            for (int wm = 0; wm < 2; ++wm)
                a[wm] = *(const bf16x8*)(h1t + (rowbase + wm * 16 + l16) * SCH + kc * 32 + q * 8);
            bf16x8 b = wpl[(kc * 2 + nt0) * 64];
#pragma unroll
            for (int wm = 0; wm < 2; ++wm)
                acc[wm] = __builtin_amdgcn_mfma_f32_16x16x32_bf16(a[wm], b, acc[wm], 0, 0, 0);
        }
#pragma unroll
        for (int wm = 0; wm < 2; ++wm) {
            int col = colbase + l16;
#pragma unroll
            for (int r = 0; r < 4; ++r) {
                int row = R0 + rowbase + wm * 16 + q * 4 + r;
                float v = acc[wm][r] * dinv[row];
                y[(long)row * 32 + col] = f2bf(v);
            }
        }
    }
}

// ================= fused gather + GEMM3 (32->128) + temporal conv1 =================
// __launch_bounds__(256, 8): force VGPR <= 64 (was 68, just over the cliff).
__global__ __launch_bounds__(256, 8) void k_gmc1(
    const uint4* __restrict__ xs,        // zs3 [TOT,32] bf16 (4 uint4/row)
    const int* __restrict__ adj,
    const int2* __restrict__ rse,
    const float* __restrict__ dinv,
    const bf16x8* __restrict__ wp3, const float* __restrict__ b3,
    const bf16x8* __restrict__ wpc1, const float* __restrict__ tb1,
    unsigned short* __restrict__ y) {    // conv1 out [TOT,128]
    constexpr int SCA = 40;              // agg tile stride (32+8)
    constexpr int SCH = 144;             // h3 tile stride
    __shared__ __attribute__((aligned(16))) unsigned short shl[66 * SCH];  // 19 KB
    unsigned short* atile = shl;         // phase 1 (80x40 = 6.4 KB)
    unsigned short* h3t   = shl;         // phase 2 (66x144), aliased

    const int R0 = blockIdx.x * 64;
    const int n0 = R0 & NMASK;
    const int tid = threadIdx.x;

    // zero atile pad rows 66..79 (read by the 5th masked row-tile)
    for (int i = tid; i < 14 * 5; i += 256) {
        int r = 66 + i / 5, c = i % 5;
        *(uint4*)(atile + r * SCA + c * 8) = make_uint4(0, 0, 0, 0);
    }

    // ---- gather phase: agg3 = (self + sum) * dinv for rows [R0-1, R0+65) ----
    for (int it = tid; it < 66 * 4; it += 256) {
        int rr = it >> 2, g = it & 3;
        int n = n0 - 1 + rr;
        float a[8] = {0.f, 0.f, 0.f, 0.f, 0.f, 0.f, 0.f, 0.f};
        if (n >= 0 && n < 4096) {
            int gr = R0 - 1 + rr;
            unpack8(xs[gr * 4 + g], a);                  // self-loop
            int2 se = rse[gr];
            int e = se.x, end = se.x + se.y;
            for (; e + 4 <= end; e += 4) {
                int s0 = adj[e], s1 = adj[e + 1], s2 = adj[e + 2], s3 = adj[e + 3];
                uint4 v0 = xs[(s0 << 2) + g];
                uint4 v1 = xs[(s1 << 2) + g];
                uint4 v2 = xs[(s2 << 2) + g];
                uint4 v3 = xs[(s3 << 2) + g];
                float f[8];
                unpack8(v0, f);
#pragma unroll
                for (int j = 0; j < 8; ++j) a[j] += f[j];
                unpack8(v1, f);
#pragma unroll
                for (int j = 0; j < 8; ++j) a[j] += f[j];
                unpack8(v2, f);
#pragma unroll
                for (int j = 0; j < 8; ++j) a[j] += f[j];
                unpack8(v3, f);
#pragma unroll
                for (int j = 0; j < 8; ++j) a[j] += f[j];
            }
            for (; e < end; ++e) {
                float f[8];
                unpack8(xs[(adj[e] << 2) + g], f);
#pragma unroll
                for (int j = 0; j < 8; ++j) a[j] += f[j];
            }
            float dv = dinv[gr];
#pragma unroll
            for (int j = 0; j < 8; ++j) a[j] *= dv;
        }
        *(uint4*)(atile + rr * SCA + g * 8) = pack8(a);
    }
    __syncthreads();

    const int lane = tid & 63;
    const int w = tid >> 6;
    const int l16 = lane & 15;
    const int q = lane >> 4;

    // ---- GEMM3: 32 -> 128 on 66 rows (reads atile into regs, barrier, h3t) ----
    {
        f32x4 acc[5][2];
#pragma unroll
        for (int rt = 0; rt < 5; ++rt)
#pragma unroll
            for (int nt = 0; nt < 2; ++nt) acc[rt][nt] = (f32x4){0.f, 0.f, 0.f, 0.f};
        const bf16x8* wpl = wp3 + lane;
        bf16x8 b[2];
        b[0] = wpl[(w * 2 + 0) * 64];
        b[1] = wpl[(w * 2 + 1) * 64];
#pragma unroll
        for (int rt = 0; rt < 5; ++rt) {
            bf16x8 a = *(const bf16x8*)(atile + (16 * rt + l16) * SCA + q * 8);
            acc[rt][0] = __builtin_amdgcn_mfma_f32_16x16x32_bf16(a, b[0], acc[rt][0], 0, 0, 0);
            acc[rt][1] = __builtin_amdgcn_mfma_f32_16x16x32_bf16(a, b[1], acc[rt][1], 0, 0, 0);
        }
        __syncthreads();   // all atile reads complete before h3t (alias) writes
#pragma unroll
        for (int rt = 0; rt < 5; ++rt) {
#pragma unroll
            for (int nt = 0; nt < 2; ++nt) {
                int col = w * 32 + nt * 16 + l16;
                float bi = b3[col];
#pragma unroll
                for (int r = 0; r < 4; ++r) {
                    int rr = 16 * rt + q * 4 + r;
                    if (rr < 66) {
                        int n = n0 - 1 + rr;
                        unsigned short v = 0;
                        if (n >= 0 && n < 4096)
                            v = f2bf(fmaxf(acc[rt][nt][r] + bi, 0.0f));
                        h3t[rr * SCH + col] = v;
                    }
                }
            }
        }
    }
    __syncthreads();

    // ---- conv1: 128->128 k=3; out row R0+j reads h3t rows j..j+2 ----
    {
        f32x4 acc[4][2];
#pragma unroll
        for (int rt = 0; rt < 4; ++rt)
#pragma unroll
            for (int nt = 0; nt < 2; ++nt) acc[rt][nt] = (f32x4){0.f, 0.f, 0.f, 0.f};
        const bf16x8* wpl = wpc1 + lane;
#pragma unroll
        for (int kc = 0; kc < 12; ++kc) {
            int tap = kc >> 2, ch = kc & 3;
            bf16x8 a[4];
#pragma unroll
            for (int rt = 0; rt < 4; ++rt)
                a[rt] = *(const bf16x8*)(h3t + (16 * rt + l16 + tap) * SCH + ch * 32 + q * 8);
            bf16x8 b0 = wpl[(kc * 8 + 2 * w + 0) * 64];
            bf16x8 b1 = wpl[(kc * 8 + 2 * w + 1) * 64];
#pragma unroll
            for (int rt = 0; rt < 4; ++rt) {
                acc[rt][0] = __builtin_amdgcn_mfma_f32_16x16x32_bf16(a[rt], b0, acc[rt][0], 0, 0, 0);
                acc[rt][1] = __builtin_amdgcn_mfma_f32_16x16x32_bf16(a[rt], b1, acc[rt][1], 0, 0, 0);
            }
        }
#pragma unroll
        for (int rt = 0; rt < 4; ++rt) {
#pragma unroll
            for (int nt = 0; nt < 2; ++nt) {
                int col = w * 32 + nt * 16 + l16;
                float bi = tb1[col];
#pragma unroll
                for (int r = 0; r < 4; ++r) {
                    int row = R0 + 16 * rt + q * 4 + r;
                    y[(long)row * 128 + col] = f2bf(fmaxf(acc[rt][nt][r] + bi, 0.0f));
                }
            }
        }
    }
}

// ================= fused conv2 (128->32) + conv3 (32->128) + heads =================
__global__ __launch_bounds__(256) void k_c23_heads(
    const unsigned short* __restrict__ x,      // conv1 output [TOT,128] bf16
    const bf16x8* __restrict__ wp2, const float* __restrict__ tb2,
    const bf16x8* __restrict__ wp3, const float* __restrict__ tb3,
    const float* __restrict__ Wpi, const float* __restrict__ bpi,
    const float* __restrict__ Wn,  const float* __restrict__ bn,
    const float* __restrict__ Wp,  const float* __restrict__ bp,
    float* __restrict__ out) {
    constexpr int SC1 = 136;
    constexpr int SC2 = 40;
    __shared__ __attribute__((aligned(16))) unsigned short shl[82 * 136 + 66 * 40];
    unsigned short* c1  = shl;                // 82 rows: global [R0-2, R0+80)
    unsigned short* c2  = shl + 82 * 136;     // 66 rows: global [R0-1, R0+65)
    unsigned short* xts = shl;                // alias (c1 dead after conv2)

    const int R0 = blockIdx.x * 64;
    const int n0 = R0 & NMASK;
    const int tid = threadIdx.x;

    for (int i = tid; i < 82 * 16; i += 256) {
        int r = i >> 4;
        int c8 = i & 15;
        int n = n0 - 2 + r;
        uint4 v = make_uint4(0, 0, 0, 0);
        if (n >= 0 && n < 4096)
            v = *(const uint4*)(x + (long)(R0 - 2 + r) * 128 + c8 * 8);
        *(uint4*)(c1 + r * SC1 + c8 * 8) = v;
    }
    __syncthreads();

    const int lane = tid & 63;
    const int w = tid >> 6;
    const int l16 = lane & 15;
    const int q = lane >> 4;

    // ---- conv2: 128->32, 5 row-tiles, wave rts {w, w+4} ----
    for (int rt = w; rt < 5; rt += 4) {
        f32x4 acc[2];
#pragma unroll
        for (int nt = 0; nt < 2; ++nt) acc[nt] = (f32x4){0.f, 0.f, 0.f, 0.f};
        const bf16x8* wpl = wp2 + lane;
#pragma unroll
        for (int kc = 0; kc < 12; ++kc) {
            int tap = kc >> 2, ch = kc & 3;
            bf16x8 a = *(const bf16x8*)(c1 + (16 * rt + l16 + tap) * SC1 + ch * 32 + q * 8);
            bf16x8 b0 = wpl[(kc * 2 + 0) * 64];
            bf16x8 b1 = wpl[(kc * 2 + 1) * 64];
            acc[0] = __builtin_amdgcn_mfma_f32_16x16x32_bf16(a, b0, acc[0], 0, 0, 0);
            acc[1] = __builtin_amdgcn_mfma_f32_16x16x32_bf16(a, b1, acc[1], 0, 0, 0);
        }
#pragma unroll
        for (int nt = 0; nt < 2; ++nt) {
            int col = nt * 16 + l16;
            float bi = tb2[col];
#pragma unroll
            for (int r = 0; r < 4; ++r) {
                int idx = 16 * rt + q * 4 + r;
                if (idx < 66) {
                    int n = n0 - 1 + idx;
                    unsigned short v = 0;
                    if (n >= 0 && n < 4096)
                        v = f2bf(fmaxf(acc[nt][r] + bi, 0.0f));
                    c2[idx * SC2 + col] = v;
                }
            }
        }
    }
    __syncthreads();

    // ---- conv3: 32->128, 4 row-tiles at R0; write xts ----
    {
        f32x4 acc[4][2];
#pragma unroll
        for (int rt = 0; rt < 4; ++rt)
#pragma unroll
            for (int nt = 0; nt < 2; ++nt) acc[rt][nt] = (f32x4){0.f, 0.f, 0.f, 0.f};
        const bf16x8* wpl = wp3 + lane;
#pragma unroll
        for (int kc = 0; kc < 3; ++kc) {
            bf16x8 a[4];
#pragma unroll
            for (int rt = 0; rt < 4; ++rt)
                a[rt] = *(const bf16x8*)(c2 + (16 * rt + l16 + kc) * SC2 + q * 8);
            bf16x8 b[2];
#pragma unroll
            for (int nt = 0; nt < 2; ++nt)
                b[nt] = wpl[(kc * 8 + 2 * w + nt) * 64];
#pragma unroll
            for (int rt = 0; rt < 4; ++rt)
#pragma unroll
                for (int nt = 0; nt < 2; ++nt)
                    acc[rt][nt] = __builtin_amdgcn_mfma_f32_16x16x32_bf16(a[rt], b[nt], acc[rt][nt], 0, 0, 0);
        }
#pragma unroll
        for (int rt = 0; rt < 4; ++rt) {
#pragma unroll
            for (int nt = 0; nt < 2; ++nt) {
                int col = w * 32 + nt * 16 + l16;
                float bi = tb3[col];
#pragma unroll
                for (int r = 0; r < 4; ++r) {
                    int row = 16 * rt + q * 4 + r;
                    xts[row * 130 + col] = f2bf(fmaxf(acc[rt][nt][r] + bi, 0.0f));
                }
            }
        }
    }
    __syncthreads();

    // ---- heads ----
    if (tid < 192) {
        int h = tid >> 6;
        int row = tid & 63;
        const float* Wh = (h == 0) ? Wpi : (h == 1) ? Wn : Wp;
        float s = 0.0f;
        const unsigned short* xr = xts + row * 130;
#pragma unroll
        for (int c2i = 0; c2i < 64; ++c2i) {
            unsigned u = *(const unsigned*)(xr + c2i * 2);
            s = fmaf(bf2f(u & 0xffffu), Wh[c2i * 2], s);
            s = fmaf(bf2f(u >> 16), Wh[c2i * 2 + 1], s);
        }
        float bb = (h == 0) ? bpi[0] : (h == 1) ? bn[0] : bp[0];
        float z = s + bb;
        float o;
        if (h == 1) o = (z > 20.0f) ? z : log1pf(expf(z));
        else        o = 1.0f / (1.0f + expf(-z));
        out[h * TOT + R0 + row] = o;
    }
}

extern "C" void kernel_launch(void* const* d_in, const int* in_sizes, int n_in,
                              void* d_out, int out_size, void* d_ws, size_t ws_size,
                              hipStream_t stream) {
    const float* x   = (const float*)d_in[0];
    const int*   ei  = (const int*)d_in[1];
    const int*   src = ei;
    const int*   dst = ei + NE;
    const float* W1 = (const float*)d_in[3];
    const float* b1 = (const float*)d_in[4];
    const float* W2 = (const float*)d_in[5];
    const float* b2 = (const float*)d_in[6];
    const float* W3 = (const float*)d_in[7];
    const float* b3 = (const float*)d_in[8];
    const float* tW1 = (const float*)d_in[9];
    const float* tb1 = (const float*)d_in[10];
    const float* tW2 = (const float*)d_in[11];
    const float* tb2 = (const float*)d_in[12];
    const float* tW3 = (const float*)d_in[13];
    const float* tb3 = (const float*)d_in[14];
    const float* Wpi = (const float*)d_in[15];
    const float* bpi = (const float*)d_in[16];
    const float* Wn  = (const float*)d_in[17];
    const float* bn  = (const float*)d_in[18];
    const float* Wp  = (const float*)d_in[19];
    const float* bp  = (const float*)d_in[20];

    // ---- workspace layout ----
    char* ws = (char*)d_ws;
    float* dinv = (float*)(ws + (0ull << 20));            // 512 KB
    int*   gcur = (int*)  (ws + (1ull << 20));            // 64 KB (line-padded)
    int2*  rse  = (int2*) (ws + (1ull << 20) + (256 << 10)); // 1 MB
    unsigned short* wpG1 = (unsigned short*)(ws + (3ull << 20));
    unsigned short* wpG2 = (unsigned short*)(ws + (3ull << 20) + (128 << 10));
    unsigned short* wpG3 = (unsigned short*)(ws + (3ull << 20) + (256 << 10));
    unsigned short* wpC1 = (unsigned short*)(ws + (3ull << 20) + (384 << 10));
    unsigned short* wpC2 = (unsigned short*)(ws + (3ull << 20) + (512 << 10));
    unsigned short* wpC3 = (unsigned short*)(ws + (3ull << 20) + (640 << 10));
    unsigned* buf = (unsigned*)(ws + (4ull << 20));       // 8 MB
    int* adj = (int*)(ws + (12ull << 20));                // 8 MB
    unsigned short* Xa = (unsigned short*)(ws + (24ull  << 20));  // 64ch  16.8 MB
    unsigned short* Xc = (unsigned short*)(ws + (80ull  << 20));  // 128ch 33.6 MB
    unsigned short* Xd = (unsigned short*)(ws + (116ull << 20));  // 32ch   8.4 MB
    unsigned short* Xe = (unsigned short*)(ws + (128ull << 20));  // 32ch   8.4 MB

    // ---- prep ----
    hipMemsetAsync(gcur, 0, NB * 32 * sizeof(int), stream);

    // ---- adjacency: bucket partition (+ fused weight packing) + per-bucket CSR ----
    PackArgs pa = { W1, W2, W3, tW1, tW2, tW3, wpG1, wpG2, wpG3, wpC1, wpC2, wpC3 };
    k_part<<<NE / EPB, 256, 0, stream>>>(src, dst, gcur, buf, pa);
    k_bcsr<<<NB, 256, 0, stream>>>(buf, gcur, adj, rse, dinv, (const float4*)x, (uint4*)Xa);

    // ---- GCN layers 1+2a fused: gather + GEMM1 + GEMM2 -> zs2 ----
    k_gmm2<<<TOT / 64, 256, 0, stream>>>((const uint4*)Xa, adj, rse, dinv,
                                         (const bf16x8*)wpG1, b1, (const bf16x8*)wpG2, Xd);

    // ---- GCN layer 2b: zs3 = relu(agg(zs2)*dinv + b2)*dinv ----
    k_gcsr<2><<<TOT * 4 / 256, 256, 0, stream>>>((const uint4*)Xd, adj, rse, dinv,
                                                 b2, (uint4*)Xe);

    // ---- GCN layer 3 + temporal conv1 fused: gather + GEMM3 + conv1 -> Xc ----
    k_gmc1<<<TOT / 64, 256, 0, stream>>>((const uint4*)Xe, adj, rse, dinv,
                                         (const bf16x8*)wpG3, b3,
                                         (const bf16x8*)wpC1, tb1, Xc);

    // ---- conv2 + conv3 + heads fused ----
    k_c23_heads<<<TOT / 64, 256, 0, stream>>>(Xc,
                                              (const bf16x8*)wpC2, tb2,
                                              (const bf16x8*)wpC3, tb3,
                                              Wpi, bpi, Wn, bn, Wp, bp, (float*)d_out);
}

// Round 15
// 259.273 us; speedup vs baseline: 1.0710x; 1.0388x over previous
//
#include <hip/hip_runtime.h>
#include <cmath>

// Problem constants (fixed by the reference)
constexpr int TOT = 131072;   // 32 graphs * 4096 nodes
constexpr int NE  = 1048576;  // edges
constexpr int NMASK = 4095;   // N-1, N=4096

// Bucketed adjacency
constexpr int NB   = 512;     // buckets (dst >> 8)
constexpr int DPB  = 256;     // dsts per bucket
constexpr int BCAP = 4096;    // slots per bucket (mean 2048)
constexpr int EPB  = 2048;    // edges per partition block

typedef __attribute__((ext_vector_type(8))) short bf16x8;
typedef __attribute__((ext_vector_type(4))) float f32x4;

// ---- bf16 helpers (RNE) ----
__device__ inline float bf2f(unsigned int u16) {
    union { unsigned int i; float f; } x; x.i = u16 << 16; return x.f;
}
__device__ inline unsigned short f2bf(float f) {
    union { float f; unsigned int i; } x; x.f = f;
    unsigned int r = (x.i + 0x7fffu + ((x.i >> 16) & 1u)) >> 16;
    return (unsigned short)r;
}
__device__ inline void unpack8(uint4 v, float* f) {
    f[0] = bf2f(v.x & 0xffffu); f[1] = bf2f(v.x >> 16);
    f[2] = bf2f(v.y & 0xffffu); f[3] = bf2f(v.y >> 16);
    f[4] = bf2f(v.z & 0xffffu); f[5] = bf2f(v.z >> 16);
    f[6] = bf2f(v.w & 0xffffu); f[7] = bf2f(v.w >> 16);
}
__device__ inline uint4 pack8(const float* f) {
    uint4 v;
    v.x = (unsigned)f2bf(f[0]) | ((unsigned)f2bf(f[1]) << 16);
    v.y = (unsigned)f2bf(f[2]) | ((unsigned)f2bf(f[3]) << 16);
    v.z = (unsigned)f2bf(f[4]) | ((unsigned)f2bf(f[5]) << 16);
    v.w = (unsigned)f2bf(f[6]) | ((unsigned)f2bf(f[7]) << 16);
    return v;
}

// ---- weight packing into MFMA B-fragment order (device helper) ----
__device__ inline void pack_one(const float* __restrict__ w, unsigned short* __restrict__ wp,
                                int CIN, int COUT, int taps, int idx) {
    int j = idx & 7;
    int L = (idx >> 3) & 63;
    int f = idx >> 9;
    int NT = COUT >> 4;
    int kc = f / NT, nt = f - kc * NT;
    int k = kc * 32 + (L >> 4) * 8 + j;
    int n = nt * 16 + (L & 15);
    float v;
    if (taps == 1) v = w[k * COUT + n];
    else { int t = k / CIN, c = k - t * CIN; v = w[(n * CIN + c) * 3 + t]; }
    wp[idx] = f2bf(v);
}

// ================= edge partition by dst bucket (+ fused weight packing) =================
struct PackArgs {
    const float *W1, *W2, *W3, *tW1, *tW2, *tW3;
    unsigned short *g1, *g2, *g3, *c1, *c2, *c3;
};
__global__ __launch_bounds__(256) void k_part(const int* __restrict__ src,
                                              const int* __restrict__ dst,
                                              int* __restrict__ gcur,
                                              unsigned* __restrict__ buf,
                                              PackArgs pa) {
    __shared__ int hist[NB];
    __shared__ int cbase[NB];
    __shared__ int lcur[NB];
    const int tid = threadIdx.x;
    const int e0 = blockIdx.x * EPB;

    for (int b = tid; b < NB; b += 256) hist[b] = 0;
    __syncthreads();
    for (int i = tid; i < EPB; i += 256)
        atomicAdd(&hist[dst[e0 + i] >> 8], 1);
    __syncthreads();
    for (int b = tid; b < NB; b += 256) {
        int c = hist[b];
        cbase[b] = (c > 0) ? atomicAdd(&gcur[b * 32], c) : 0;
        lcur[b] = 0;
    }
    __syncthreads();
    for (int i = tid; i < EPB; i += 256) {
        int e = e0 + i;
        int d = dst[e];
        int b = d >> 8;
        int p = atomicAdd(&lcur[b], 1);
        buf[b * BCAP + cbase[b] + p] = ((unsigned)src[e] << 8) | (unsigned)(d & 255);
    }
    // fused weight packing
    int gid = blockIdx.x * 256 + tid;
    if      (gid <  8192) pack_one(pa.W1,  pa.g1, 64, 128, 1, gid);
    else if (gid < 12288) pack_one(pa.W2,  pa.g2, 128, 32, 1, gid - 8192);
    else if (gid < 16384) pack_one(pa.W3,  pa.g3, 32, 128, 1, gid - 12288);
    else if (gid < 65536) pack_one(pa.tW1, pa.c1, 128, 128, 3, gid - 16384);
    else if (gid < 77824) pack_one(pa.tW2, pa.c2, 128, 32, 3, gid - 65536);
    else if (gid < 90112) pack_one(pa.tW3, pa.c3, 32, 128, 3, gid - 77824);
}

// ================= per-bucket CSR build + dinv + fused x*dinv scaling =================
__global__ __launch_bounds__(256) void k_bcsr(const unsigned* __restrict__ buf,
                                              const int* __restrict__ gcur,
                                              int* __restrict__ adj,
                                              int2* __restrict__ rse,
                                              float* __restrict__ dinv,
                                              const float4* __restrict__ x,
                                              uint4* __restrict__ xsc) {
    __shared__ int cnt[DPB];
    __shared__ int start[DPB];
    __shared__ int cur[DPB];
    __shared__ int sc[DPB];
    const int b = blockIdx.x;
    const int tid = threadIdx.x;
    cnt[tid] = 0;
    __syncthreads();
    const int n = gcur[b * 32];
    const unsigned* eb = buf + b * BCAP;
    for (int i = tid; i < n; i += 256)
        atomicAdd(&cnt[eb[i] & 255u], 1);
    __syncthreads();
    int v = cnt[tid];
    sc[tid] = v;
    __syncthreads();
    for (int off = 1; off < 256; off <<= 1) {
        int a = sc[tid];
        int p = (tid >= off) ? sc[tid - off] : 0;
        __syncthreads();
        sc[tid] = a + p;
        __syncthreads();
    }
    int st = sc[tid] - v;
    start[tid] = st;
    cur[tid] = 0;
    int d = (b << 8) + tid;
    rse[d] = make_int2(b * BCAP + st, v);
    dinv[d] = rsqrtf((float)v + 1.0f);   // +1 self-loop
    __syncthreads();
    for (int i = tid; i < n; i += 256) {
        unsigned w = eb[i];
        int dl = (int)(w & 255u);
        int p = atomicAdd(&cur[dl], 1);
        adj[b * BCAP + start[dl] + p] = (int)(w >> 8);
    }
    // fused: xs = x * dinv -> bf16 for this bucket's 256 rows
    for (int i = tid; i < DPB * 8; i += 256) {
        int rl = i >> 3;
        int t = (b << 11) + i;                 // global uint4 index (row*8+g)
        float dv = rsqrtf((float)cnt[rl] + 1.0f);
        float4 v0 = x[t * 2], v1 = x[t * 2 + 1];
        float f[8] = { v0.x * dv, v0.y * dv, v0.z * dv, v0.w * dv,
                       v1.x * dv, v1.y * dv, v1.z * dv, v1.w * dv };
        xsc[t] = pack8(f);
    }
}

// ================= standalone CSR gather (layer-2 epilogue) =================
template<int LC>
__global__ __launch_bounds__(256, 8) void k_gcsr(const uint4* __restrict__ xs,
                                                 const int* __restrict__ adj,
                                                 const int2* __restrict__ rse,
                                                 const float* __restrict__ dinv,
                                                 const float* __restrict__ bias,
                                                 uint4* __restrict__ out) {
    int t = blockIdx.x * 256 + threadIdx.x;   // t < TOT << LC
    int d = t >> LC;
    int g = t & ((1 << LC) - 1);
    float a[8];
    unpack8(xs[t], a);                        // self-loop term
    int2 se = rse[d];
    int e = se.x, end = se.x + se.y;
    for (; e + 4 <= end; e += 4) {
        int s0 = adj[e], s1 = adj[e + 1], s2 = adj[e + 2], s3 = adj[e + 3];
        uint4 v0 = xs[(s0 << LC) + g];
        uint4 v1 = xs[(s1 << LC) + g];
        uint4 v2 = xs[(s2 << LC) + g];
        uint4 v3 = xs[(s3 << LC) + g];
        float f[8];
        unpack8(v0, f);
#pragma unroll
        for (int j = 0; j < 8; ++j) a[j] += f[j];
        unpack8(v1, f);
#pragma unroll
        for (int j = 0; j < 8; ++j) a[j] += f[j];
        unpack8(v2, f);
#pragma unroll
        for (int j = 0; j < 8; ++j) a[j] += f[j];
        unpack8(v3, f);
#pragma unroll
        for (int j = 0; j < 8; ++j) a[j] += f[j];
    }
    for (; e < end; ++e) {
        float f[8];
        unpack8(xs[(adj[e] << LC) + g], f);
#pragma unroll
        for (int j = 0; j < 8; ++j) a[j] += f[j];
    }
    float dv = dinv[d];
#pragma unroll
    for (int j = 0; j < 8; ++j)
        a[j] = fmaxf(fmaf(a[j], dv, bias[g * 8 + j]), 0.0f) * dv;
    out[t] = pack8(a);
}

// ================= fused gather + GEMM1 (64->128) + GEMM2 (128->32) =================
// (256,8) forces VGPR<=64; GEMM1 loads ONE A-fragment at a time (a[4] array was
// 16 live VGPRs -> 4) so the bound fits without scratch spill (round-14
// WRITE_SIZE showed +10 MB spill traffic under the same bound).
__global__ __launch_bounds__(256, 8) void k_gmm2(const uint4* __restrict__ xs,
                                                 const int* __restrict__ adj,
                                                 const int2* __restrict__ rse,
                                                 const float* __restrict__ dinv,
                                                 const bf16x8* __restrict__ wp1,
                                                 const float* __restrict__ b1,
                                                 const bf16x8* __restrict__ wp2,
                                                 unsigned short* __restrict__ y) {
    constexpr int CIN = 64;
    constexpr int ROWS = 64;
    constexpr int SC  = CIN + 8;          // 72
    constexpr int SCH = 144;
    constexpr int NV = CIN / 8;
    constexpr int VPT = NV / 4;
    __shared__ __attribute__((aligned(16))) unsigned short shl[ROWS * SCH];  // 18.4 KB
    unsigned short* tile1 = shl;          // phase 1 (64x72)
    unsigned short* h1t   = shl;          // phase 2 (64x144), aliased

    const int R0 = blockIdx.x * ROWS;
    const int tid = threadIdx.x;

    // ---- gather/stage phase ----
    {
        int r = R0 + (tid >> 2);
        int g = tid & 3;
        const uint4* base = xs + (long)r * NV + g * VPT;
        float a[VPT * 8];
#pragma unroll
        for (int v = 0; v < VPT; ++v) unpack8(base[v], a + v * 8);   // self-loop
        int2 se = rse[r];
        int e = se.x, end = se.x + se.y;
        for (; e + 4 <= end; e += 4) {
            int s0 = adj[e], s1 = adj[e + 1], s2 = adj[e + 2], s3 = adj[e + 3];
            const uint4* p0 = xs + (long)s0 * NV + g * VPT;
            const uint4* p1 = xs + (long)s1 * NV + g * VPT;
            const uint4* p2 = xs + (long)s2 * NV + g * VPT;
            const uint4* p3 = xs + (long)s3 * NV + g * VPT;
            uint4 v0[VPT], v1[VPT], v2[VPT], v3[VPT];
#pragma unroll
            for (int v = 0; v < VPT; ++v) { v0[v] = p0[v]; v1[v] = p1[v]; v2[v] = p2[v]; v3[v] = p3[v]; }
            float f[VPT * 8];
#pragma unroll
            for (int v = 0; v < VPT; ++v) unpack8(v0[v], f + v * 8);
#pragma unroll
            for (int j = 0; j < VPT * 8; ++j) a[j] += f[j];
#pragma unroll
            for (int v = 0; v < VPT; ++v) unpack8(v1[v], f + v * 8);
#pragma unroll
            for (int j = 0; j < VPT * 8; ++j) a[j] += f[j];
#pragma unroll
            for (int v = 0; v < VPT; ++v) unpack8(v2[v], f + v * 8);
#pragma unroll
            for (int j = 0; j < VPT * 8; ++j) a[j] += f[j];
#pragma unroll
            for (int v = 0; v < VPT; ++v) unpack8(v3[v], f + v * 8);
#pragma unroll
            for (int j = 0; j < VPT * 8; ++j) a[j] += f[j];
        }
        for (; e < end; ++e) {
            const uint4* p0 = xs + (long)adj[e] * NV + g * VPT;
            float f[VPT * 8];
#pragma unroll
            for (int v = 0; v < VPT; ++v) unpack8(p0[v], f + v * 8);
#pragma unroll
            for (int j = 0; j < VPT * 8; ++j) a[j] += f[j];
        }
        float dv = dinv[r];
#pragma unroll
        for (int j = 0; j < VPT * 8; ++j) a[j] *= dv;
        uint4* dst4 = (uint4*)(tile1 + (tid >> 2) * SC + g * VPT * 8);
#pragma unroll
        for (int v = 0; v < VPT; ++v) dst4[v] = pack8(a + v * 8);
    }
    __syncthreads();

    const int lane = tid & 63;
    const int w = tid >> 6;
    const int l16 = lane & 15;
    const int q = lane >> 4;

    // ---- GEMM1: 64 -> 128 (one A-fragment live at a time) ----
    {
        f32x4 acc[4][2];
#pragma unroll
        for (int wm = 0; wm < 4; ++wm)
#pragma unroll
            for (int nt = 0; nt < 2; ++nt) acc[wm][nt] = (f32x4){0.f, 0.f, 0.f, 0.f};
        const bf16x8* wpl = wp1 + lane;
        const int nt0 = w * 2;
#pragma unroll
        for (int kc = 0; kc < 2; ++kc) {
            bf16x8 b[2];
#pragma unroll
            for (int nt = 0; nt < 2; ++nt)
                b[nt] = wpl[(kc * 8 + nt0 + nt) * 64];
#pragma unroll
            for (int wm = 0; wm < 4; ++wm) {
                bf16x8 a = *(const bf16x8*)(tile1 + (wm * 16 + l16) * SC + kc * 32 + q * 8);
                acc[wm][0] = __builtin_amdgcn_mfma_f32_16x16x32_bf16(a, b[0], acc[wm][0], 0, 0, 0);
                acc[wm][1] = __builtin_amdgcn_mfma_f32_16x16x32_bf16(a, b[1], acc[wm][1], 0, 0, 0);
            }
        }
        __syncthreads();   // all tile1 reads complete before h1t (alias) writes
#pragma unroll
        for (int wm = 0; wm < 4; ++wm) {
#pragma unroll
            for (int nt = 0; nt < 2; ++nt) {
                int col = w * 32 + nt * 16 + l16;
                float bi = b1[col];
#pragma unroll
                for (int r = 0; r < 4; ++r) {
                    int row = wm * 16 + q * 4 + r;
                    h1t[row * SCH + col] = f2bf(fmaxf(acc[wm][nt][r] + bi, 0.0f));
                }
            }
        }
    }
    __syncthreads();

    // ---- GEMM2: 128 -> 32 ----
    {
        const int colbase = (w & 1) * 16;
        const int rowbase = (w >> 1) * 32;
        const int nt0 = colbase >> 4;
        f32x4 acc[2];
#pragma unroll
        for (int wm = 0; wm < 2; ++wm) acc[wm] = (f32x4){0.f, 0.f, 0.f, 0.f};
        const bf16x8* wpl = wp2 + lane;
#pragma unroll
        for (int kc = 0; kc < 4; ++kc) {
            bf16x8 b = wpl[(kc * 2 + nt0) * 64];
#pragma unroll
            for (int wm = 0; wm < 2; ++wm) {
                bf16x8 a = *(const bf16x8*)(h1t + (rowbase + wm * 16 + l16) * SCH + kc * 32 + q * 8);
                acc[wm] = __builtin_amdgcn_mfma_f32_16x16x32_bf16(a, b, acc[wm], 0, 0, 0);
            }
        }
#pragma unroll
        for (int wm = 0; wm < 2; ++wm) {
            int col = colbase + l16;
#pragma unroll
            for (int r = 0; r < 4; ++r) {
                int row = R0 + rowbase + wm * 16 + q * 4 + r;
                float v = acc[wm][r] * dinv[row];
                y[(long)row * 32 + col] = f2bf(v);
            }
        }
    }
}

// ================= fused gather + GEMM3 (32->128) + temporal conv1 =================
// (256,8); conv1 loads one A-fragment at a time (was a[4] = 16 live VGPRs).
__global__ __launch_bounds__(256, 8) void k_gmc1(
    const uint4* __restrict__ xs,        // zs3 [TOT,32] bf16 (4 uint4/row)
    const int* __restrict__ adj,
    const int2* __restrict__ rse,
    const float* __restrict__ dinv,
    const bf16x8* __restrict__ wp3, const float* __restrict__ b3,
    const bf16x8* __restrict__ wpc1, const float* __restrict__ tb1,
    unsigned short* __restrict__ y) {    // conv1 out [TOT,128]
    constexpr int SCA = 40;              // agg tile stride (32+8)
    constexpr int SCH = 144;             // h3 tile stride
    __shared__ __attribute__((aligned(16))) unsigned short shl[66 * SCH];  // 19 KB
    unsigned short* atile = shl;         // phase 1 (80x40 = 6.4 KB)
    unsigned short* h3t   = shl;         // phase 2 (66x144), aliased

    const int R0 = blockIdx.x * 64;
    const int n0 = R0 & NMASK;
    const int tid = threadIdx.x;

    // zero atile pad rows 66..79 (read by the 5th masked row-tile)
    for (int i = tid; i < 14 * 5; i += 256) {
        int r = 66 + i / 5, c = i % 5;
        *(uint4*)(atile + r * SCA + c * 8) = make_uint4(0, 0, 0, 0);
    }

    // ---- gather phase: agg3 = (self + sum) * dinv for rows [R0-1, R0+65) ----
    for (int it = tid; it < 66 * 4; it += 256) {
        int rr = it >> 2, g = it & 3;
        int n = n0 - 1 + rr;
        float a[8] = {0.f, 0.f, 0.f, 0.f, 0.f, 0.f, 0.f, 0.f};
        if (n >= 0 && n < 4096) {
            int gr = R0 - 1 + rr;
            unpack8(xs[gr * 4 + g], a);                  // self-loop
            int2 se = rse[gr];
            int e = se.x, end = se.x + se.y;
            for (; e + 4 <= end; e += 4) {
                int s0 = adj[e], s1 = adj[e + 1], s2 = adj[e + 2], s3 = adj[e + 3];
                uint4 v0 = xs[(s0 << 2) + g];
                uint4 v1 = xs[(s1 << 2) + g];
                uint4 v2 = xs[(s2 << 2) + g];
                uint4 v3 = xs[(s3 << 2) + g];
                float f[8];
                unpack8(v0, f);
#pragma unroll
                for (int j = 0; j < 8; ++j) a[j] += f[j];
                unpack8(v1, f);
#pragma unroll
                for (int j = 0; j < 8; ++j) a[j] += f[j];
                unpack8(v2, f);
#pragma unroll
                for (int j = 0; j < 8; ++j) a[j] += f[j];
                unpack8(v3, f);
#pragma unroll
                for (int j = 0; j < 8; ++j) a[j] += f[j];
            }
            for (; e < end; ++e) {
                float f[8];
                unpack8(xs[(adj[e] << 2) + g], f);
#pragma unroll
                for (int j = 0; j < 8; ++j) a[j] += f[j];
            }
            float dv = dinv[gr];
#pragma unroll
            for (int j = 0; j < 8; ++j) a[j] *= dv;
        }
        *(uint4*)(atile + rr * SCA + g * 8) = pack8(a);
    }
    __syncthreads();

    const int lane = tid & 63;
    const int w = tid >> 6;
    const int l16 = lane & 15;
    const int q = lane >> 4;

    // ---- GEMM3: 32 -> 128 on 66 rows (reads atile into regs, barrier, h3t) ----
    {
        f32x4 acc[5][2];
#pragma unroll
        for (int rt = 0; rt < 5; ++rt)
#pragma unroll
            for (int nt = 0; nt < 2; ++nt) acc[rt][nt] = (f32x4){0.f, 0.f, 0.f, 0.f};
        const bf16x8* wpl = wp3 + lane;
        bf16x8 b[2];
        b[0] = wpl[(w * 2 + 0) * 64];
        b[1] = wpl[(w * 2 + 1) * 64];
#pragma unroll
        for (int rt = 0; rt < 5; ++rt) {
            bf16x8 a = *(const bf16x8*)(atile + (16 * rt + l16) * SCA + q * 8);
            acc[rt][0] = __builtin_amdgcn_mfma_f32_16x16x32_bf16(a, b[0], acc[rt][0], 0, 0, 0);
            acc[rt][1] = __builtin_amdgcn_mfma_f32_16x16x32_bf16(a, b[1], acc[rt][1], 0, 0, 0);
        }
        __syncthreads();   // all atile reads complete before h3t (alias) writes
#pragma unroll
        for (int rt = 0; rt < 5; ++rt) {
#pragma unroll
            for (int nt = 0; nt < 2; ++nt) {
                int col = w * 32 + nt * 16 + l16;
                float bi = b3[col];
#pragma unroll
                for (int r = 0; r < 4; ++r) {
                    int rr = 16 * rt + q * 4 + r;
                    if (rr < 66) {
                        int n = n0 - 1 + rr;
                        unsigned short v = 0;
                        if (n >= 0 && n < 4096)
                            v = f2bf(fmaxf(acc[rt][nt][r] + bi, 0.0f));
                        h3t[rr * SCH + col] = v;
                    }
                }
            }
        }
    }
    __syncthreads();

    // ---- conv1: 128->128 k=3; one A-fragment live at a time ----
    {
        f32x4 acc[4][2];
#pragma unroll
        for (int rt = 0; rt < 4; ++rt)
#pragma unroll
            for (int nt = 0; nt < 2; ++nt) acc[rt][nt] = (f32x4){0.f, 0.f, 0.f, 0.f};
        const bf16x8* wpl = wpc1 + lane;
#pragma unroll
        for (int kc = 0; kc < 12; ++kc) {
            int tap = kc >> 2, ch = kc & 3;
            bf16x8 b0 = wpl[(kc * 8 + 2 * w + 0) * 64];
            bf16x8 b1 = wpl[(kc * 8 + 2 * w + 1) * 64];
#pragma unroll
            for (int rt = 0; rt < 4; ++rt) {
                bf16x8 a = *(const bf16x8*)(h3t + (16 * rt + l16 + tap) * SCH + ch * 32 + q * 8);
                acc[rt][0] = __builtin_amdgcn_mfma_f32_16x16x32_bf16(a, b0, acc[rt][0], 0, 0, 0);
                acc[rt][1] = __builtin_amdgcn_mfma_f32_16x16x32_bf16(a, b1, acc[rt][1], 0, 0, 0);
            }
        }
#pragma unroll
        for (int rt = 0; rt < 4; ++rt) {
#pragma unroll
            for (int nt = 0; nt < 2; ++nt) {
                int col = w * 32 + nt * 16 + l16;
                float bi = tb1[col];
#pragma unroll
                for (int r = 0; r < 4; ++r) {
                    int row = R0 + 16 * rt + q * 4 + r;
                    y[(long)row * 128 + col] = f2bf(fmaxf(acc[rt][nt][r] + bi, 0.0f));
                }
            }
        }
    }
}

// ================= fused conv2 (128->32) + conv3 (32->128) + heads =================
__global__ __launch_bounds__(256) void k_c23_heads(
    const unsigned short* __restrict__ x,      // conv1 output [TOT,128] bf16
    const bf16x8* __restrict__ wp2, const float* __restrict__ tb2,
    const bf16x8* __restrict__ wp3, const float* __restrict__ tb3,
    const float* __restrict__ Wpi, const float* __restrict__ bpi,
    const float* __restrict__ Wn,  const float* __restrict__ bn,
    const float* __restrict__ Wp,  const float* __restrict__ bp,
    float* __restrict__ out) {
    constexpr int SC1 = 136;
    constexpr int SC2 = 40;
    __shared__ __attribute__((aligned(16))) unsigned short shl[82 * 136 + 66 * 40];
    unsigned short* c1  = shl;                // 82 rows: global [R0-2, R0+80)
    unsigned short* c2  = shl + 82 * 136;     // 66 rows: global [R0-1, R0+65)
    unsigned short* xts = shl;                // alias (c1 dead after conv2)

    const int R0 = blockIdx.x * 64;
    const int n0 = R0 & NMASK;
    const int tid = threadIdx.x;

    for (int i = tid; i < 82 * 16; i += 256) {
        int r = i >> 4;
        int c8 = i & 15;
        int n = n0 - 2 + r;
        uint4 v = make_uint4(0, 0, 0, 0);
        if (n >= 0 && n < 4096)
            v = *(const uint4*)(x + (long)(R0 - 2 + r) * 128 + c8 * 8);
        *(uint4*)(c1 + r * SC1 + c8 * 8) = v;
    }
    __syncthreads();

    const int lane = tid & 63;
    const int w = tid >> 6;
    const int l16 = lane & 15;
    const int q = lane >> 4;

    // ---- conv2: 128->32, 5 row-tiles, wave rts {w, w+4} ----
    for (int rt = w; rt < 5; rt += 4) {
        f32x4 acc[2];
#pragma unroll
        for (int nt = 0; nt < 2; ++nt) acc[nt] = (f32x4){0.f, 0.f, 0.f, 0.f};
        const bf16x8* wpl = wp2 + lane;
#pragma unroll
        for (int kc = 0; kc < 12; ++kc) {
            int tap = kc >> 2, ch = kc & 3;
            bf16x8 a = *(const bf16x8*)(c1 + (16 * rt + l16 + tap) * SC1 + ch * 32 + q * 8);
            bf16x8 b0 = wpl[(kc * 2 + 0) * 64];
            bf16x8 b1 = wpl[(kc * 2 + 1) * 64];
            acc[0] = __builtin_amdgcn_mfma_f32_16x16x32_bf16(a, b0, acc[0], 0, 0, 0);
            acc[1] = __builtin_amdgcn_mfma_f32_16x16x32_bf16(a, b1, acc[1], 0, 0, 0);
        }
#pragma unroll
        for (int nt = 0; nt < 2; ++nt) {
            int col = nt * 16 + l16;
            float bi = tb2[col];
#pragma unroll
            for (int r = 0; r < 4; ++r) {
                int idx = 16 * rt + q * 4 + r;
                if (idx < 66) {
                    int n = n0 - 1 + idx;
                    unsigned short v = 0;
                    if (n >= 0 && n < 4096)
                        v = f2bf(fmaxf(acc[nt][r] + bi, 0.0f));
                    c2[idx * SC2 + col] = v;
                }
            }
        }
    }
    __syncthreads();

    // ---- conv3: 32->128, 4 row-tiles at R0; write xts ----
    {
        f32x4 acc[4][2];
#pragma unroll
        for (int rt = 0; rt < 4; ++rt)
#pragma unroll
            for (int nt = 0; nt < 2; ++nt) acc[rt][nt] = (f32x4){0.f, 0.f, 0.f, 0.f};
        const bf16x8* wpl = wp3 + lane;
#pragma unroll
        for (int kc = 0; kc < 3; ++kc) {
            bf16x8 b[2];
#pragma unroll
            for (int nt = 0; nt < 2; ++nt)
                b[nt] = wpl[(kc * 8 + 2 * w + nt) * 64];
#pragma unroll
            for (int rt = 0; rt < 4; ++rt) {
                bf16x8 a = *(const bf16x8*)(c2 + (16 * rt + l16 + kc) * SC2 + q * 8);
                acc[rt][0] = __builtin_amdgcn_mfma_f32_16x16x32_bf16(a, b[0], acc[rt][0], 0, 0, 0);
                acc[rt][1] = __builtin_amdgcn_mfma_f32_16x16x32_bf16(a, b[1], acc[rt][1], 0, 0, 0);
            }
        }
#pragma unroll
        for (int rt = 0; rt < 4; ++rt) {
#pragma unroll
            for (int nt = 0; nt < 2; ++nt) {
                int col = w * 32 + nt * 16 + l16;
                float bi = tb3[col];
#pragma unroll
                for (int r = 0; r < 4; ++r) {
                    int row = 16 * rt + q * 4 + r;
                    xts[row * 130 + col] = f2bf(fmaxf(acc[rt][nt][r] + bi, 0.0f));
                }
            }
        }
    }
    __syncthreads();

    // ---- heads ----
    if (tid < 192) {
        int h = tid >> 6;
        int row = tid & 63;
        const float* Wh = (h == 0) ? Wpi : (h == 1) ? Wn : Wp;
        float s = 0.0f;
        const unsigned short* xr = xts + row * 130;
#pragma unroll
        for (int c2i = 0; c2i < 64; ++c2i) {
            unsigned u = *(const unsigned*)(xr + c2i * 2);
            s = fmaf(bf2f(u & 0xffffu), Wh[c2i * 2], s);
            s = fmaf(bf2f(u >> 16), Wh[c2i * 2 + 1], s);
        }
        float bb = (h == 0) ? bpi[0] : (h == 1) ? bn[0] : bp[0];
        float z = s + bb;
        float o;
        if (h == 1) o = (z > 20.0f) ? z : log1pf(expf(z));
        else        o = 1.0f / (1.0f + expf(-z));
        out[h * TOT + R0 + row] = o;
    }
}

extern "C" void kernel_launch(void* const* d_in, const int* in_sizes, int n_in,
                              void* d_out, int out_size, void* d_ws, size_t ws_size,
                              hipStream_t stream) {
    const float* x   = (const float*)d_in[0];
    const int*   ei  = (const int*)d_in[1];
    const int*   src = ei;
    const int*   dst = ei + NE;
    const float* W1 = (const float*)d_in[3];
    const float* b1 = (const float*)d_in[4];
    const float* W2 = (const float*)d_in[5];
    const float* b2 = (const float*)d_in[6];
    const float* W3 = (const float*)d_in[7];
    const float* b3 = (const float*)d_in[8];
    const float* tW1 = (const float*)d_in[9];
    const float* tb1 = (const float*)d_in[10];
    const float* tW2 = (const float*)d_in[11];
    const float* tb2 = (const float*)d_in[12];
    const float* tW3 = (const float*)d_in[13];
    const float* tb3 = (const float*)d_in[14];
    const float* Wpi = (const float*)d_in[15];
    const float* bpi = (const float*)d_in[16];
    const float* Wn  = (const float*)d_in[17];
    const float* bn  = (const float*)d_in[18];
    const float* Wp  = (const float*)d_in[19];
    const float* bp  = (const float*)d_in[20];

    // ---- workspace layout ----
    char* ws = (char*)d_ws;
    float* dinv = (float*)(ws + (0ull << 20));            // 512 KB
    int*   gcur = (int*)  (ws + (1ull << 20));            // 64 KB (line-padded)
    int2*  rse  = (int2*) (ws + (1ull << 20) + (256 << 10)); // 1 MB
    unsigned short* wpG1 = (unsigned short*)(ws + (3ull << 20));
    unsigned short* wpG2 = (unsigned short*)(ws + (3ull << 20) + (128 << 10));
    unsigned short* wpG3 = (unsigned short*)(ws + (3ull << 20) + (256 << 10));
    unsigned short* wpC1 = (unsigned short*)(ws + (3ull << 20) + (384 << 10));
    unsigned short* wpC2 = (unsigned short*)(ws + (3ull << 20) + (512 << 10));
    unsigned short* wpC3 = (unsigned short*)(ws + (3ull << 20) + (640 << 10));
    unsigned* buf = (unsigned*)(ws + (4ull << 20));       // 8 MB
    int* adj = (int*)(ws + (12ull << 20));                // 8 MB
    unsigned short* Xa = (unsigned short*)(ws + (24ull  << 20));  // 64ch  16.8 MB
    unsigned short* Xc = (unsigned short*)(ws + (80ull  << 20));  // 128ch 33.6 MB
    unsigned short* Xd = (unsigned short*)(ws + (116ull << 20));  // 32ch   8.4 MB
    unsigned short* Xe = (unsigned short*)(ws + (128ull << 20));  // 32ch   8.4 MB

    // ---- prep ----
    hipMemsetAsync(gcur, 0, NB * 32 * sizeof(int), stream);

    // ---- adjacency: bucket partition (+ fused weight packing) + per-bucket CSR ----
    PackArgs pa = { W1, W2, W3, tW1, tW2, tW3, wpG1, wpG2, wpG3, wpC1, wpC2, wpC3 };
    k_part<<<NE / EPB, 256, 0, stream>>>(src, dst, gcur, buf, pa);
    k_bcsr<<<NB, 256, 0, stream>>>(buf, gcur, adj, rse, dinv, (const float4*)x, (uint4*)Xa);

    // ---- GCN layers 1+2a fused: gather + GEMM1 + GEMM2 -> zs2 ----
    k_gmm2<<<TOT / 64, 256, 0, stream>>>((const uint4*)Xa, adj, rse, dinv,
                                         (const bf16x8*)wpG1, b1, (const bf16x8*)wpG2, Xd);

    // ---- GCN layer 2b: zs3 = relu(agg(zs2)*dinv + b2)*dinv ----
    k_gcsr<2><<<TOT * 4 / 256, 256, 0, stream>>>((const uint4*)Xd, adj, rse, dinv,
                                                 b2, (uint4*)Xe);

    // ---- GCN layer 3 + temporal conv1 fused: gather + GEMM3 + conv1 -> Xc ----
    k_gmc1<<<TOT / 64, 256, 0, stream>>>((const uint4*)Xe, adj, rse, dinv,
                                         (const bf16x8*)wpG3, b3,
                                         (const bf16x8*)wpC1, tb1, Xc);

    // ---- conv2 + conv3 + heads fused ----
    k_c23_heads<<<TOT / 64, 256, 0, stream>>>(Xc,
                                              (const bf16x8*)wpC2, tb2,
                                              (const bf16x8*)wpC3, tb3,
                                              Wpi, bpi, Wn, bn, Wp, bp, (float*)d_out);
}